// Round 10
// baseline (454.000 us; speedup 1.0000x reference)
//
#include <hip/hip_runtime.h>
#include <math.h>

#define NB 4
#define NC 256
#define NCI 128
#define NC2 512
#define NPOS 4096
#define ISPLIT 8

using bf16x8 = __attribute__((ext_vector_type(8))) short;
using f32x4  = __attribute__((ext_vector_type(4))) float;

__device__ inline unsigned short f2bf(float f) {
  unsigned int u = __float_as_uint(f);
  u = (u + 0x7fffu + ((u >> 16) & 1u)) >> 16;
  return (unsigned short)u;
}
__device__ inline float bf2f(short s) {
  return __uint_as_float(((unsigned int)(unsigned short)s) << 16);
}

// ---------------- cast 4 weight tensors fp32 -> bf16 ----------------
__global__ void k_cast4(const float* __restrict__ s0, short* __restrict__ d0, int n0,
                        const float* __restrict__ s1, short* __restrict__ d1, int n1,
                        const float* __restrict__ s2, short* __restrict__ d2, int n2,
                        const float* __restrict__ s3, short* __restrict__ d3, int n3) {
  int i = blockIdx.x * 256 + threadIdx.x;
  if (i < n0) { d0[i] = (short)f2bf(s0[i]); return; } i -= n0;
  if (i < n1) { d1[i] = (short)f2bf(s1[i]); return; } i -= n1;
  if (i < n2) { d2[i] = (short)f2bf(s2[i]); return; } i -= n2;
  if (i < n3) { d3[i] = (short)f2bf(s3[i]); }
}

// ---------------- fused transpose-cast for x, x_dsm, x0 ----------------
// in [b][R][C] f32 -> out [b][C][R] bf16; y selects tensor+row-tile.
__global__ __launch_bounds__(256) void k_tcast_all(
    const float* __restrict__ x, const float* __restrict__ xdsm,
    const float* __restrict__ x0, short* __restrict__ xT,
    short* __restrict__ xdT, short* __restrict__ x0T) {
  __shared__ float t[64][65];
  const int tid = threadIdx.x;
  const int y = blockIdx.y, c0 = blockIdx.x * 64, b = blockIdx.z;
  const float* in; short* out; int R, r0;
  if (y < 4)      { in = x;    out = xT;  R = NC;  r0 = y * 64; }
  else if (y < 8) { in = xdsm; out = xdT; R = NC;  r0 = (y - 4) * 64; }
  else            { in = x0;   out = x0T; R = NC2; r0 = (y - 8) * 64; }
  const size_t inBs = (size_t)R * NPOS, outBs = (size_t)NPOS * R;
  {
    int r = tid >> 2, cc = (tid & 3) * 16;
    const float* ib = in + (size_t)b * inBs + (size_t)(r0 + r) * NPOS + c0 + cc;
#pragma unroll
    for (int i = 0; i < 4; ++i) {
      float4 v = *(const float4*)(ib + i * 4);
      t[r][cc + i * 4 + 0] = v.x; t[r][cc + i * 4 + 1] = v.y;
      t[r][cc + i * 4 + 2] = v.z; t[r][cc + i * 4 + 3] = v.w;
    }
  }
  __syncthreads();
  {
    int c = tid >> 2, rr = (tid & 3) * 16;
    __align__(16) short v[16];
#pragma unroll
    for (int i = 0; i < 16; ++i) v[i] = (short)f2bf(t[rr + i][c]);
    short* ob = out + (size_t)b * outBs + (size_t)(c0 + c) * R + r0 + rr;
    *(int4*)(ob) = *(const int4*)(v);
    *(int4*)(ob + 8) = *(const int4*)(v + 8);
  }
}

// ---------------- sum two bf16 partials [cc][i] -> transpose [i][cc] bf16 ------
__global__ __launch_bounds__(256) void k_tcast2(
    const short* __restrict__ inA, const short* __restrict__ inB,
    short* __restrict__ out) {
  __shared__ float t[64][65];
  const int tid = threadIdx.x;
  const int r0 = blockIdx.y * 64, c0 = blockIdx.x * 64, b = blockIdx.z;
  {
    int r = tid >> 2, cc = (tid & 3) * 16;
    size_t base = (size_t)b * NC * NPOS + (size_t)(r0 + r) * NPOS + c0 + cc;
    bf16x8 a0 = *(const bf16x8*)(inA + base);
    bf16x8 a1 = *(const bf16x8*)(inA + base + 8);
    bf16x8 b0 = *(const bf16x8*)(inB + base);
    bf16x8 b1 = *(const bf16x8*)(inB + base + 8);
#pragma unroll
    for (int i = 0; i < 8; ++i) {
      t[r][cc + i] = bf2f(a0[i]) + bf2f(b0[i]);
      t[r][cc + 8 + i] = bf2f(a1[i]) + bf2f(b1[i]);
    }
  }
  __syncthreads();
  {
    int c = tid >> 2, rr = (tid & 3) * 16;
    __align__(16) short v[16];
#pragma unroll
    for (int i = 0; i < 16; ++i) v[i] = (short)f2bf(t[rr + i][c]);
    short* ob = out + (size_t)b * (size_t)NPOS * NC + (size_t)(c0 + c) * NC + r0 + rr;
    *(int4*)(ob) = *(const int4*)(v);
    *(int4*)(ob + 8) = *(const int4*)(v + 8);
  }
}

// ---------------- generic bf16 MFMA GEMM ----------------
template<bool OUT_BF16, bool HAS_RES>
__global__ __launch_bounds__(256, 2) void k_gemm(
    const short* __restrict__ A, const short* __restrict__ B,
    void* __restrict__ outv, const float* __restrict__ res,
    int K, int sN, size_t aBs, size_t bBs, size_t oBs) {
  __shared__ short As[2][64 * 64];
  __shared__ short Bs_[2][64 * 64];
  const int tid = threadIdx.x, lane = tid & 63, w = tid >> 6;
  const int x = lane & 15, q = lane >> 4;
  const int wm = (w & 1) * 32, wn = (w >> 1) * 32;
  const int n0 = blockIdx.x * 64, m0 = blockIdx.y * 64, b = blockIdx.z;
  const short* Ab = A + (size_t)b * aBs + (size_t)m0 * K;
  const short* Bb = B + (size_t)b * bBs + (size_t)n0 * K;
  const int r = tid >> 2, cth = tid & 3;
  f32x4 acc[2][2];
  acc[0][0] = acc[0][1] = acc[1][0] = acc[1][1] = (f32x4){0.f, 0.f, 0.f, 0.f};
  int4 ra[2], rb[2];
  const int NK = K >> 6;
#define GLOAD(kt)                                                              \
  { _Pragma("unroll") for (int i = 0; i < 2; ++i) {                            \
      ra[i] = *(const int4*)(Ab + (size_t)r * K + (kt) * 64 + (cth + i * 4) * 8); \
      rb[i] = *(const int4*)(Bb + (size_t)r * K + (kt) * 64 + (cth + i * 4) * 8); } }
#define GWRITE(buf)                                                            \
  { _Pragma("unroll") for (int i = 0; i < 2; ++i) {                            \
      *(int4*)(&As[buf][r * 64 + (((cth + i * 4) ^ (r & 7)) * 8)]) = ra[i];    \
      *(int4*)(&Bs_[buf][r * 64 + (((cth + i * 4) ^ (r & 7)) * 8)]) = rb[i]; } }
  GLOAD(0); GWRITE(0); __syncthreads();
  int cur = 0;
  for (int kt = 0; kt < NK; ++kt) {
    if (kt + 1 < NK) GLOAD(kt + 1);
    bf16x8 af[2][2], bfr[2][2];
#pragma unroll
    for (int ms = 0; ms < 2; ++ms) {
      int rowm = wm + ms * 16 + x;
#pragma unroll
      for (int ks = 0; ks < 2; ++ks)
        af[ms][ks] = *(const bf16x8*)(&As[cur][rowm * 64 + (((ks * 4 + q) ^ (rowm & 7)) * 8)]);
    }
#pragma unroll
    for (int ns = 0; ns < 2; ++ns) {
      int rown = wn + ns * 16 + x;
#pragma unroll
      for (int ks = 0; ks < 2; ++ks)
        bfr[ns][ks] = *(const bf16x8*)(&Bs_[cur][rown * 64 + (((ks * 4 + q) ^ (rown & 7)) * 8)]);
    }
#pragma unroll
    for (int ms = 0; ms < 2; ++ms)
#pragma unroll
      for (int ns = 0; ns < 2; ++ns)
#pragma unroll
        for (int ks = 0; ks < 2; ++ks)
          acc[ms][ns] = __builtin_amdgcn_mfma_f32_16x16x32_bf16(
              af[ms][ks], bfr[ns][ks], acc[ms][ns], 0, 0, 0);
    if (kt + 1 < NK) GWRITE(cur ^ 1);
    __syncthreads();
    cur ^= 1;
  }
#pragma unroll
  for (int ms = 0; ms < 2; ++ms)
#pragma unroll
    for (int ns = 0; ns < 2; ++ns) {
      int n = n0 + wn + ns * 16 + x;
      int m = m0 + wm + ms * 16 + q * 4;
      size_t off = (size_t)b * oBs + (size_t)n * sN + m;
      if (OUT_BF16) {
        __align__(8) short pv[4];
#pragma unroll
        for (int j = 0; j < 4; ++j) pv[j] = (short)f2bf(acc[ms][ns][j]);
        *(uint2*)((short*)outv + off) = *(const uint2*)pv;
      } else {
        float4 v = {acc[ms][ns][0], acc[ms][ns][1], acc[ms][ns][2], acc[ms][ns][3]};
        if (HAS_RES) {
          float4 rv = *(const float4*)(res + off);
          v.x += rv.x; v.y += rv.y; v.z += rv.z; v.w += rv.w;
        }
        *(float4*)((float*)outv + off) = v;
      }
    }
#undef GLOAD
#undef GWRITE
}

// ---------------- partial l[j]: plsum[b][iy][j] = sum_{i in chunk} exp(s[i][j]) ----
__global__ __launch_bounds__(256, 4) void k_lsum(
    const short* __restrict__ phiB, const short* __restrict__ thetaB,
    float* __restrict__ plsum) {
  __shared__ short thT[2][64 * 128];
  const int tid = threadIdx.x, lane = tid & 63, w = tid >> 6;
  const int x = lane & 15, q = lane >> 4;
  const int j0 = blockIdx.x * 64, iy = blockIdx.y, b = blockIdx.z;
  const short* phb = phiB + (size_t)b * NPOS * NCI;
  const short* thb = thetaB + (size_t)b * NPOS * NCI + (size_t)iy * (NPOS / ISPLIT) * NCI;
  bf16x8 af[4];
  {
    const short* pr = phb + (size_t)(j0 + w * 16 + x) * NCI;
#pragma unroll
    for (int kk = 0; kk < 4; ++kk) af[kk] = *(const bf16x8*)(pr + kk * 32 + q * 8);
  }
  float lsum[4] = {0.f, 0.f, 0.f, 0.f};
  int4 rt[4];
  const int NIT = NPOS / ISPLIT / 64;   // 8
#define LSUM_LOAD(it)                                                         \
  { _Pragma("unroll") for (int r = 0; r < 4; ++r) {                           \
      int s = tid + r * 256; int row = s >> 4, c = s & 15;                    \
      rt[r] = *(const int4*)(thb + (size_t)((it) * 64 + row) * NCI + c * 8); } }
#define LSUM_WRITE(buf)                                                       \
  { _Pragma("unroll") for (int r = 0; r < 4; ++r) {                           \
      int s = tid + r * 256; int row = s >> 4, c = s & 15;                    \
      *(int4*)(&thT[buf][row * 128 + ((c ^ (row & 7)) * 8)]) = rt[r]; } }
  LSUM_LOAD(0); LSUM_WRITE(0); __syncthreads();
  int cur = 0;
  for (int it = 0; it < NIT; ++it) {
    if (it + 1 < NIT) LSUM_LOAD(it + 1);
#pragma unroll
    for (int ii = 0; ii < 4; ++ii) {
      f32x4 s = {0.f, 0.f, 0.f, 0.f};
      int row = ii * 16 + x;
      int sw = row & 7;
#pragma unroll
      for (int kk = 0; kk < 4; ++kk) {
        bf16x8 bfv = *(const bf16x8*)(&thT[cur][row * 128 + (((kk * 4 + q) ^ sw) * 8)]);
        s = __builtin_amdgcn_mfma_f32_16x16x32_bf16(af[kk], bfv, s, 0, 0, 0);
      }
#pragma unroll
      for (int r = 0; r < 4; ++r) lsum[r] += __expf(s[r]);
    }
    if (it + 1 < NIT) LSUM_WRITE(cur ^ 1);
    __syncthreads();
    cur ^= 1;
  }
#pragma unroll
  for (int m = 1; m < 16; m <<= 1)
#pragma unroll
    for (int r = 0; r < 4; ++r) lsum[r] += __shfl_xor(lsum[r], m);
  if (x == 0) {
#pragma unroll
    for (int r = 0; r < 4; ++r)
      plsum[((size_t)(b * ISPLIT + iy) << 12) + j0 + w * 16 + 4 * q + r] = lsum[r];
  }
#undef LSUM_LOAD
#undef LSUM_WRITE
}

// ---------------- combine partials -> linv ----------------
__global__ void k_lcomb(const float* __restrict__ plsum, float* __restrict__ linv) {
  int i = blockIdx.x * 256 + threadIdx.x;   // NB*NPOS
  int b = i >> 12, j = i & (NPOS - 1);
  float s = 0.f;
#pragma unroll
  for (int t = 0; t < ISPLIT; ++t) s += plsum[((size_t)(b * ISPLIT + t) << 12) + j];
  linv[i] = 1.0f / s;
}

// ---------------- attention: omidP[jh][b][cc][i] = sum_{j in half} P*g -------
// S phase (R6-identical + linv fold): wave w computes S^T 32j x 16i (i-block w),
// P -> shared pT[64 i][32 j]. PV phase: wave w owns cc-quarter [64w,64w+64) x 64 i.
__global__ __launch_bounds__(256, 2) void k_attn(
    const short* __restrict__ phiB, const short* __restrict__ thetaB,
    const short* __restrict__ gB, const float* __restrict__ linv,
    short* __restrict__ omidP) {
  __shared__ short phiT[2][32 * 128];   // 8KB each
  __shared__ short gT[2][256 * 32];     // 16KB each
  __shared__ short pT[64 * 32];         // 4KB shared [i][j], swizzled
  const int tid = threadIdx.x, lane = tid & 63, w = tid >> 6;
  const int x = lane & 15, q = lane >> 4;
  const int i0 = blockIdx.x * 64, jh = blockIdx.y, b = blockIdx.z;
  const short* phb = phiB + (size_t)b * NPOS * NCI;
  const short* thb = thetaB + (size_t)b * NPOS * NCI;
  const short* gb = gB + (size_t)b * NC * NPOS;
  const float* lvb = linv + ((size_t)b << 12);
  short* om = omidP + ((size_t)(jh * NB + b)) * NC * NPOS;

  bf16x8 tf[4];
  {
    const short* tr = thb + (size_t)(i0 + w * 16 + x) * NCI;
#pragma unroll
    for (int kk = 0; kk < 4; ++kk) tf[kk] = *(const bf16x8*)(tr + kk * 32 + q * 8);
  }
  f32x4 acc[4][4];   // [f: i-frag][cl: cc-frag], cc = w*64 + cl*16 + x
#pragma unroll
  for (int i = 0; i < 4; ++i)
#pragma unroll
    for (int j = 0; j < 4; ++j) acc[i][j] = (f32x4){0.f, 0.f, 0.f, 0.f};

  const int px = (x >> 1) & 3;                 // pT swizzle key
  const int sgx = (x & 3) ^ ((x >> 2) & 1);    // gT read swizzle key
  int4 rphi[2], rg[4];
  const int NT = 64;
  const int jbase = jh * 64;
#define ATTN_LOAD(jt)                                                          \
  { _Pragma("unroll") for (int r = 0; r < 2; ++r) {                            \
      int s = tid + r * 256; int row = s >> 4, c = s & 15;                     \
      rphi[r] = *(const int4*)(phb + (size_t)((jbase + (jt)) * 32 + row) * NCI + c * 8); } \
    _Pragma("unroll") for (int r = 0; r < 4; ++r) {                            \
      int s = tid + r * 256; int cc = s >> 2, c4 = s & 3;                      \
      rg[r] = *(const int4*)(gb + (size_t)cc * NPOS + (jbase + (jt)) * 32 + c4 * 8); } }
#define ATTN_WRITE(buf)                                                        \
  { _Pragma("unroll") for (int r = 0; r < 2; ++r) {                            \
      int s = tid + r * 256; int row = s >> 4, c = s & 15;                     \
      *(int4*)(&phiT[buf][row * 128 + ((c ^ (row & 7)) * 8)]) = rphi[r]; }     \
    _Pragma("unroll") for (int r = 0; r < 4; ++r) {                            \
      int s = tid + r * 256; int cc = s >> 2, c4 = s & 3;                      \
      int sw = (cc & 3) ^ ((cc >> 2) & 1);                                     \
      *(int4*)(&gT[buf][cc * 32 + ((c4 ^ sw) * 8)]) = rg[r]; } }
  ATTN_LOAD(0); ATTN_WRITE(0); __syncthreads();
  int cur = 0;
  for (int jt = 0; jt < NT; ++jt) {
    if (jt + 1 < NT) ATTN_LOAD(jt + 1);
    // ---- S phase: wave w -> 32 j x 16 i (i = i0 + w*16 + x) ----
    {
      const short* PH = &phiT[cur][0];
#pragma unroll
      for (int jsub = 0; jsub < 2; ++jsub) {
        f32x4 s = {0.f, 0.f, 0.f, 0.f};
        int row = jsub * 16 + x;
        int sw = row & 7;
#pragma unroll
        for (int kk = 0; kk < 4; ++kk) {
          bf16x8 a = *(const bf16x8*)(PH + row * 128 + (((kk * 4 + q) ^ sw) * 8));
          s = __builtin_amdgcn_mfma_f32_16x16x32_bf16(a, tf[kk], s, 0, 0, 0);
        }
        // lane holds S^T[j=jsub*16+4q+r][i = i0 + w*16 + x]
        float4 lv = *(const float4*)(lvb + (jbase + jt) * 32 + jsub * 16 + 4 * q);
        unsigned short p0 = f2bf(__expf(s[0]) * lv.x);
        unsigned short p1 = f2bf(__expf(s[1]) * lv.y);
        unsigned short p2 = f2bf(__expf(s[2]) * lv.z);
        unsigned short p3 = f2bf(__expf(s[3]) * lv.w);
        unsigned int lo = (unsigned int)p0 | ((unsigned int)p1 << 16);
        unsigned int hi = (unsigned int)p2 | ((unsigned int)p3 << 16);
        int irow = w * 16 + x;
        int byteoff = (irow * 64 + jsub * 32 + q * 8) ^ (px << 4);
        *(uint2*)((char*)pT + byteoff) = make_uint2(lo, hi);
      }
    }
    __syncthreads();   // pT complete for cross-wave PV reads
    // ---- PV phase: wave w -> cc in [64w, 64w+64), all 64 i ----
    {
      const short* GT = &gT[cur][0];
      bf16x8 ap[4];
#pragma unroll
      for (int f = 0; f < 4; ++f)
        ap[f] = *(const bf16x8*)((const char*)pT + (f * 16 + x) * 64 + ((q ^ px) << 4));
#pragma unroll
      for (int cl = 0; cl < 4; ++cl) {
        int grow = w * 64 + cl * 16 + x;
        bf16x8 bg = *(const bf16x8*)(GT + grow * 32 + ((q ^ sgx) * 8));
#pragma unroll
        for (int f = 0; f < 4; ++f)
          acc[f][cl] = __builtin_amdgcn_mfma_f32_16x16x32_bf16(ap[f], bg, acc[f][cl], 0, 0, 0);
      }
    }
    if (jt + 1 < NT) ATTN_WRITE(cur ^ 1);
    __syncthreads();   // protects pT overwrite + staging buffers
    cur ^= 1;
  }
  // store bf16: D[i=4q+r][cc=x-frag]; om is [cc][i]
#pragma unroll
  for (int f = 0; f < 4; ++f)
#pragma unroll
    for (int cl = 0; cl < 4; ++cl) {
      __align__(8) short pv[4];
#pragma unroll
      for (int j = 0; j < 4; ++j) pv[j] = (short)f2bf(acc[f][cl][j]);
      size_t o = (size_t)(w * 64 + cl * 16 + x) * NPOS + i0 + f * 16 + 4 * q;
      *(uint2*)(om + o) = *(const uint2*)pv;
    }
#undef ATTN_LOAD
#undef ATTN_WRITE
}

extern "C" void kernel_launch(void* const* d_in, const int* in_sizes, int n_in,
                              void* d_out, int out_size, void* d_ws, size_t ws_size,
                              hipStream_t stream) {
  (void)in_sizes; (void)n_in; (void)out_size; (void)ws_size;
  const float* x0      = (const float*)d_in[0];
  const float* x       = (const float*)d_in[1];
  const float* x_dsm   = (const float*)d_in[2];
  const float* w_phi   = (const float*)d_in[3];
  const float* w_theta = (const float*)d_in[4];
  const float* w_g     = (const float*)d_in[5];
  const float* w_mask  = (const float*)d_in[6];
  float* outp = (float*)d_out;

  short* sp = (short*)d_ws;
  short* wb_phi   = sp; sp += 32768;
  short* wb_theta = sp; sp += 32768;
  short* wb_g     = sp; sp += 131072;
  short* wb_mask  = sp; sp += 131072;
  short* xT   = sp; sp += (size_t)NB * NPOS * NC;          // 8MB
  short* xdT  = sp; sp += (size_t)NB * NPOS * NC;          // 8MB
  short* x0T  = sp; sp += (size_t)NB * NPOS * NC2;         // 16MB
  short* phiB   = sp; sp += (size_t)NB * NPOS * NCI;       // 4MB
  short* thetaB = sp; sp += (size_t)NB * NPOS * NCI;       // 4MB
  short* gBuf   = sp; sp += (size_t)NB * NC * NPOS;        // 8MB
  float* linv = (float*)sp; sp += 2 * (size_t)NB * NPOS;
  float* plsum = (float*)sp;                               // [b][ISPLIT][NPOS]
  short* omidP = xT;       // 2 bf16 partials x 8MB = 16MB, aliases dead xT/xdT
  short* omidT = phiB;     // 8MB bf16 [b][p][cc], aliases dead phiB/thetaB

  k_cast4<<<dim3(1280), 256, 0, stream>>>(w_phi, wb_phi, 32768,
                                          w_theta, wb_theta, 32768,
                                          w_g, wb_g, 131072,
                                          w_mask, wb_mask, 131072);

  k_tcast_all<<<dim3(64, 16, NB), 256, 0, stream>>>(x, x_dsm, x0, xT, xdT, x0T);

  k_gemm<true, false><<<dim3(64, 2, NB), 256, 0, stream>>>(
      wb_phi, xT, phiB, nullptr, NC, NCI, 0, (size_t)NPOS * NC, (size_t)NPOS * NCI);
  k_gemm<true, false><<<dim3(64, 2, NB), 256, 0, stream>>>(
      wb_theta, xdT, thetaB, nullptr, NC, NCI, 0, (size_t)NPOS * NC, (size_t)NPOS * NCI);
  k_gemm<true, false><<<dim3(4, 64, NB), 256, 0, stream>>>(
      x0T, wb_g, gBuf, nullptr, NC2, NPOS, (size_t)NPOS * NC2, 0, (size_t)NC * NPOS);

  k_lsum<<<dim3(NPOS / 64, ISPLIT, NB), 256, 0, stream>>>(phiB, thetaB, plsum);
  k_lcomb<<<dim3(NB * NPOS / 256), 256, 0, stream>>>(plsum, linv);

  k_attn<<<dim3(64, 2, NB), 256, 0, stream>>>(phiB, thetaB, gBuf, linv, omidP);

  k_tcast2<<<dim3(64, 4, NB), 256, 0, stream>>>(
      omidP, omidP + (size_t)NB * NC * NPOS, omidT);

  k_gemm<false, true><<<dim3(8, 64, NB), 256, 0, stream>>>(
      omidT, wb_mask, outp, x0, NC, NPOS, (size_t)NPOS * NC, 0, (size_t)NC2 * NPOS);
}

// Round 12
// 251.908 us; speedup vs baseline: 1.8022x; 1.8022x over previous
//
#include <hip/hip_runtime.h>
#include <math.h>

#define NB 4
#define NC 256
#define NCI 128
#define NC2 512
#define NPOS 4096
#define ISPLIT 8

using bf16x8 = __attribute__((ext_vector_type(8))) short;
using f32x4  = __attribute__((ext_vector_type(4))) float;

__device__ inline unsigned short f2bf(float f) {
  unsigned int u = __float_as_uint(f);
  u = (u + 0x7fffu + ((u >> 16) & 1u)) >> 16;
  return (unsigned short)u;
}
__device__ inline float bf2f(short s) {
  return __uint_as_float(((unsigned int)(unsigned short)s) << 16);
}

// ---------------- cast 4 weight tensors fp32 -> bf16 ----------------
__global__ void k_cast4(const float* __restrict__ s0, short* __restrict__ d0, int n0,
                        const float* __restrict__ s1, short* __restrict__ d1, int n1,
                        const float* __restrict__ s2, short* __restrict__ d2, int n2,
                        const float* __restrict__ s3, short* __restrict__ d3, int n3) {
  int i = blockIdx.x * 256 + threadIdx.x;
  if (i < n0) { d0[i] = (short)f2bf(s0[i]); return; } i -= n0;
  if (i < n1) { d1[i] = (short)f2bf(s1[i]); return; } i -= n1;
  if (i < n2) { d2[i] = (short)f2bf(s2[i]); return; } i -= n2;
  if (i < n3) { d3[i] = (short)f2bf(s3[i]); }
}

// ---------------- fused transpose-cast for x, x_dsm, x0 ----------------
__global__ __launch_bounds__(256) void k_tcast_all(
    const float* __restrict__ x, const float* __restrict__ xdsm,
    const float* __restrict__ x0, short* __restrict__ xT,
    short* __restrict__ xdT, short* __restrict__ x0T) {
  __shared__ float t[64][65];
  const int tid = threadIdx.x;
  const int y = blockIdx.y, c0 = blockIdx.x * 64, b = blockIdx.z;
  const float* in; short* out; int R, r0;
  if (y < 4)      { in = x;    out = xT;  R = NC;  r0 = y * 64; }
  else if (y < 8) { in = xdsm; out = xdT; R = NC;  r0 = (y - 4) * 64; }
  else            { in = x0;   out = x0T; R = NC2; r0 = (y - 8) * 64; }
  const size_t inBs = (size_t)R * NPOS, outBs = (size_t)NPOS * R;
  {
    int r = tid >> 2, cc = (tid & 3) * 16;
    const float* ib = in + (size_t)b * inBs + (size_t)(r0 + r) * NPOS + c0 + cc;
#pragma unroll
    for (int i = 0; i < 4; ++i) {
      float4 v = *(const float4*)(ib + i * 4);
      t[r][cc + i * 4 + 0] = v.x; t[r][cc + i * 4 + 1] = v.y;
      t[r][cc + i * 4 + 2] = v.z; t[r][cc + i * 4 + 3] = v.w;
    }
  }
  __syncthreads();
  {
    int c = tid >> 2, rr = (tid & 3) * 16;
    __align__(16) short v[16];
#pragma unroll
    for (int i = 0; i < 16; ++i) v[i] = (short)f2bf(t[rr + i][c]);
    short* ob = out + (size_t)b * outBs + (size_t)(c0 + c) * R + r0 + rr;
    *(int4*)(ob) = *(const int4*)(v);
    *(int4*)(ob + 8) = *(const int4*)(v + 8);
  }
}

// ---------------- sum 4 bf16 partials [p][b][cc][i] -> transpose [b][i][cc] bf16
__global__ __launch_bounds__(256) void k_tcast4(
    const short* __restrict__ inP, short* __restrict__ out) {
  __shared__ float t[64][65];
  const int tid = threadIdx.x;
  const int r0 = blockIdx.y * 64, c0 = blockIdx.x * 64, b = blockIdx.z;
  {
    int r = tid >> 2, cc = (tid & 3) * 16;
    float tacc[16] = {};
#pragma unroll
    for (int p = 0; p < 4; ++p) {
      const short* ib = inP + ((size_t)p * NB + b) * NC * NPOS +
                        (size_t)(r0 + r) * NPOS + c0 + cc;
      bf16x8 a = *(const bf16x8*)(ib);
      bf16x8 a2 = *(const bf16x8*)(ib + 8);
#pragma unroll
      for (int i = 0; i < 8; ++i) { tacc[i] += bf2f(a[i]); tacc[8 + i] += bf2f(a2[i]); }
    }
#pragma unroll
    for (int i = 0; i < 16; ++i) t[r][cc + i] = tacc[i];
  }
  __syncthreads();
  {
    int c = tid >> 2, rr = (tid & 3) * 16;
    __align__(16) short v[16];
#pragma unroll
    for (int i = 0; i < 16; ++i) v[i] = (short)f2bf(t[rr + i][c]);
    short* ob = out + (size_t)b * (size_t)NPOS * NC + (size_t)(c0 + c) * NC + r0 + rr;
    *(int4*)(ob) = *(const int4*)(v);
    *(int4*)(ob + 8) = *(const int4*)(v + 8);
  }
}

// ---------------- generic bf16 MFMA GEMM ----------------
template<bool OUT_BF16, bool HAS_RES>
__global__ __launch_bounds__(256, 2) void k_gemm(
    const short* __restrict__ A, const short* __restrict__ B,
    void* __restrict__ outv, const float* __restrict__ res,
    int K, int sN, size_t aBs, size_t bBs, size_t oBs) {
  __shared__ short As[2][64 * 64];
  __shared__ short Bs_[2][64 * 64];
  const int tid = threadIdx.x, lane = tid & 63, w = tid >> 6;
  const int x = lane & 15, q = lane >> 4;
  const int wm = (w & 1) * 32, wn = (w >> 1) * 32;
  const int n0 = blockIdx.x * 64, m0 = blockIdx.y * 64, b = blockIdx.z;
  const short* Ab = A + (size_t)b * aBs + (size_t)m0 * K;
  const short* Bb = B + (size_t)b * bBs + (size_t)n0 * K;
  const int r = tid >> 2, cth = tid & 3;
  f32x4 acc[2][2];
  acc[0][0] = acc[0][1] = acc[1][0] = acc[1][1] = (f32x4){0.f, 0.f, 0.f, 0.f};
  int4 ra[2], rb[2];
  const int NK = K >> 6;
#define GLOAD(kt)                                                              \
  { _Pragma("unroll") for (int i = 0; i < 2; ++i) {                            \
      ra[i] = *(const int4*)(Ab + (size_t)r * K + (kt) * 64 + (cth + i * 4) * 8); \
      rb[i] = *(const int4*)(Bb + (size_t)r * K + (kt) * 64 + (cth + i * 4) * 8); } }
#define GWRITE(buf)                                                            \
  { _Pragma("unroll") for (int i = 0; i < 2; ++i) {                            \
      *(int4*)(&As[buf][r * 64 + (((cth + i * 4) ^ (r & 7)) * 8)]) = ra[i];    \
      *(int4*)(&Bs_[buf][r * 64 + (((cth + i * 4) ^ (r & 7)) * 8)]) = rb[i]; } }
  GLOAD(0); GWRITE(0); __syncthreads();
  int cur = 0;
  for (int kt = 0; kt < NK; ++kt) {
    if (kt + 1 < NK) GLOAD(kt + 1);
    bf16x8 af[2][2], bfr[2][2];
#pragma unroll
    for (int ms = 0; ms < 2; ++ms) {
      int rowm = wm + ms * 16 + x;
#pragma unroll
      for (int ks = 0; ks < 2; ++ks)
        af[ms][ks] = *(const bf16x8*)(&As[cur][rowm * 64 + (((ks * 4 + q) ^ (rowm & 7)) * 8)]);
    }
#pragma unroll
    for (int ns = 0; ns < 2; ++ns) {
      int rown = wn + ns * 16 + x;
#pragma unroll
      for (int ks = 0; ks < 2; ++ks)
        bfr[ns][ks] = *(const bf16x8*)(&Bs_[cur][rown * 64 + (((ks * 4 + q) ^ (rown & 7)) * 8)]);
    }
#pragma unroll
    for (int ms = 0; ms < 2; ++ms)
#pragma unroll
      for (int ns = 0; ns < 2; ++ns)
#pragma unroll
        for (int ks = 0; ks < 2; ++ks)
          acc[ms][ns] = __builtin_amdgcn_mfma_f32_16x16x32_bf16(
              af[ms][ks], bfr[ns][ks], acc[ms][ns], 0, 0, 0);
    if (kt + 1 < NK) GWRITE(cur ^ 1);
    __syncthreads();
    cur ^= 1;
  }
#pragma unroll
  for (int ms = 0; ms < 2; ++ms)
#pragma unroll
    for (int ns = 0; ns < 2; ++ns) {
      int n = n0 + wn + ns * 16 + x;
      int m = m0 + wm + ms * 16 + q * 4;
      size_t off = (size_t)b * oBs + (size_t)n * sN + m;
      if (OUT_BF16) {
        __align__(8) short pv[4];
#pragma unroll
        for (int j = 0; j < 4; ++j) pv[j] = (short)f2bf(acc[ms][ns][j]);
        *(uint2*)((short*)outv + off) = *(const uint2*)pv;
      } else {
        float4 v = {acc[ms][ns][0], acc[ms][ns][1], acc[ms][ns][2], acc[ms][ns][3]};
        if (HAS_RES) {
          float4 rv = *(const float4*)(res + off);
          v.x += rv.x; v.y += rv.y; v.z += rv.z; v.w += rv.w;
        }
        *(float4*)((float*)outv + off) = v;
      }
    }
#undef GLOAD
#undef GWRITE
}

// ---------------- partial l[j]: plsum[b][iy][j] = sum_{i in chunk} exp(s[i][j]) ----
__global__ __launch_bounds__(256, 4) void k_lsum(
    const short* __restrict__ phiB, const short* __restrict__ thetaB,
    float* __restrict__ plsum) {
  __shared__ short thT[2][64 * 128];
  const int tid = threadIdx.x, lane = tid & 63, w = tid >> 6;
  const int x = lane & 15, q = lane >> 4;
  const int j0 = blockIdx.x * 64, iy = blockIdx.y, b = blockIdx.z;
  const short* phb = phiB + (size_t)b * NPOS * NCI;
  const short* thb = thetaB + (size_t)b * NPOS * NCI + (size_t)iy * (NPOS / ISPLIT) * NCI;
  bf16x8 af[4];
  {
    const short* pr = phb + (size_t)(j0 + w * 16 + x) * NCI;
#pragma unroll
    for (int kk = 0; kk < 4; ++kk) af[kk] = *(const bf16x8*)(pr + kk * 32 + q * 8);
  }
  float lsum[4] = {0.f, 0.f, 0.f, 0.f};
  int4 rt[4];
  const int NIT = NPOS / ISPLIT / 64;   // 8
#define LSUM_LOAD(it)                                                         \
  { _Pragma("unroll") for (int r = 0; r < 4; ++r) {                           \
      int s = tid + r * 256; int row = s >> 4, c = s & 15;                    \
      rt[r] = *(const int4*)(thb + (size_t)((it) * 64 + row) * NCI + c * 8); } }
#define LSUM_WRITE(buf)                                                       \
  { _Pragma("unroll") for (int r = 0; r < 4; ++r) {                           \
      int s = tid + r * 256; int row = s >> 4, c = s & 15;                    \
      *(int4*)(&thT[buf][row * 128 + ((c ^ (row & 7)) * 8)]) = rt[r]; } }
  LSUM_LOAD(0); LSUM_WRITE(0); __syncthreads();
  int cur = 0;
  for (int it = 0; it < NIT; ++it) {
    if (it + 1 < NIT) LSUM_LOAD(it + 1);
#pragma unroll
    for (int ii = 0; ii < 4; ++ii) {
      f32x4 s = {0.f, 0.f, 0.f, 0.f};
      int row = ii * 16 + x;
      int sw = row & 7;
#pragma unroll
      for (int kk = 0; kk < 4; ++kk) {
        bf16x8 bfv = *(const bf16x8*)(&thT[cur][row * 128 + (((kk * 4 + q) ^ sw) * 8)]);
        s = __builtin_amdgcn_mfma_f32_16x16x32_bf16(af[kk], bfv, s, 0, 0, 0);
      }
#pragma unroll
      for (int r = 0; r < 4; ++r) lsum[r] += __expf(s[r]);
    }
    if (it + 1 < NIT) LSUM_WRITE(cur ^ 1);
    __syncthreads();
    cur ^= 1;
  }
#pragma unroll
  for (int m = 1; m < 16; m <<= 1)
#pragma unroll
    for (int r = 0; r < 4; ++r) lsum[r] += __shfl_xor(lsum[r], m);
  if (x == 0) {
#pragma unroll
    for (int r = 0; r < 4; ++r)
      plsum[((size_t)(b * ISPLIT + iy) << 12) + j0 + w * 16 + 4 * q + r] = lsum[r];
  }
#undef LSUM_LOAD
#undef LSUM_WRITE
}

// ---------------- combine partials -> linv ----------------
__global__ void k_lcomb(const float* __restrict__ plsum, float* __restrict__ linv) {
  int i = blockIdx.x * 256 + threadIdx.x;   // NB*NPOS
  int b = i >> 12, j = i & (NPOS - 1);
  float s = 0.f;
#pragma unroll
  for (int t = 0; t < ISPLIT; ++t) s += plsum[((size_t)(b * ISPLIT + t) << 12) + j];
  linv[i] = 1.0f / s;
}

// ---------------- fold linv into g: gB[cc][p] *= linv[p] ----------------
__global__ void k_scale_g(short* __restrict__ gB, const float* __restrict__ linv) {
  size_t e = ((size_t)blockIdx.x * 256 + threadIdx.x) * 8;
  int b = (int)(e >> 20);
  int p = (int)(e & (NPOS - 1));
  __align__(16) short v[8];
  *(int4*)v = *(const int4*)(gB + e);
  const float* lv = linv + ((size_t)b << 12) + p;
#pragma unroll
  for (int k = 0; k < 8; ++k) v[k] = (short)f2bf(bf2f(v[k]) * lv[k]);
  *(int4*)(gB + e) = *(const int4*)v;
}

// ---------------- attention (R6-proven structure, j-quarters, bf16 partials) ----
// omidP[jq][b][cc][i] = sum_{j in quarter} P[i][j] * g'[cc][j]
__global__ __launch_bounds__(256, 3) void k_attn(
    const short* __restrict__ phiB, const short* __restrict__ thetaB,
    const short* __restrict__ gB, short* __restrict__ omidP) {
  __shared__ short phiT[2][32 * 128];
  __shared__ short gT[2][256 * 32];
  __shared__ short pT[4][16 * 32];
  const int tid = threadIdx.x, lane = tid & 63, w = tid >> 6;
  const int x = lane & 15, q = lane >> 4;
  const int i0 = blockIdx.x * 64, jq = blockIdx.y, b = blockIdx.z;
  const short* phb = phiB + (size_t)b * NPOS * NCI;
  const short* thb = thetaB + (size_t)b * NPOS * NCI;
  const short* gb = gB + (size_t)b * NC * NPOS;
  short* om = omidP + ((size_t)(jq * NB + b)) * NC * NPOS;

  bf16x8 tf[4];
  {
    const short* tr = thb + (size_t)(i0 + w * 16 + x) * NCI;
#pragma unroll
    for (int kk = 0; kk < 4; ++kk) tf[kk] = *(const bf16x8*)(tr + kk * 32 + q * 8);
  }
  f32x4 acc[16];
#pragma unroll
  for (int i = 0; i < 16; ++i) acc[i] = (f32x4){0.f, 0.f, 0.f, 0.f};

  const int sgx = (x & 3) ^ ((x >> 2) & 1);
  int4 rphi[2], rg[4];
  const int NT = 32;                 // 32 j-tiles of 32 per quarter
  const int jbase = jq * 32;
#define ATTN_LOAD(jt)                                                          \
  { _Pragma("unroll") for (int r = 0; r < 2; ++r) {                            \
      int s = tid + r * 256; int row = s >> 4, c = s & 15;                     \
      rphi[r] = *(const int4*)(phb + (size_t)((jbase + (jt)) * 32 + row) * NCI + c * 8); } \
    _Pragma("unroll") for (int r = 0; r < 4; ++r) {                            \
      int s = tid + r * 256; int cc = s >> 2, c4 = s & 3;                      \
      rg[r] = *(const int4*)(gb + (size_t)cc * NPOS + (jbase + (jt)) * 32 + c4 * 8); } }
#define ATTN_WRITE(buf)                                                        \
  { _Pragma("unroll") for (int r = 0; r < 2; ++r) {                            \
      int s = tid + r * 256; int row = s >> 4, c = s & 15;                     \
      *(int4*)(&phiT[buf][row * 128 + ((c ^ (row & 7)) * 8)]) = rphi[r]; }     \
    _Pragma("unroll") for (int r = 0; r < 4; ++r) {                            \
      int s = tid + r * 256; int cc = s >> 2, c4 = s & 3;                      \
      int sw = (cc & 3) ^ ((cc >> 2) & 1);                                     \
      *(int4*)(&gT[buf][cc * 32 + ((c4 ^ sw) * 8)]) = rg[r]; } }
  ATTN_LOAD(0); ATTN_WRITE(0); __syncthreads();
  int cur = 0;
  for (int jt = 0; jt < NT; ++jt) {
    if (jt + 1 < NT) ATTN_LOAD(jt + 1);
    {
      const short* PH = &phiT[cur][0];
      const short* GT = &gT[cur][0];
      short* PW = &pT[w][0];
#pragma unroll
      for (int jsub = 0; jsub < 2; ++jsub) {
        f32x4 s = {0.f, 0.f, 0.f, 0.f};
        int row = jsub * 16 + x;
        int sw = row & 7;
#pragma unroll
        for (int kk = 0; kk < 4; ++kk) {
          bf16x8 a = *(const bf16x8*)(PH + row * 128 + (((kk * 4 + q) ^ sw) * 8));
          s = __builtin_amdgcn_mfma_f32_16x16x32_bf16(a, tf[kk], s, 0, 0, 0);
        }
        unsigned short p0 = f2bf(__expf(s[0]));
        unsigned short p1 = f2bf(__expf(s[1]));
        unsigned short p2 = f2bf(__expf(s[2]));
        unsigned short p3 = f2bf(__expf(s[3]));
        unsigned int lo = (unsigned int)p0 | ((unsigned int)p1 << 16);
        unsigned int hi = (unsigned int)p2 | ((unsigned int)p3 << 16);
        int byteoff = (x * 64 + jsub * 32 + q * 8) ^ ((((x >> 1) & 3)) << 4);
        *(uint2*)((char*)PW + byteoff) = make_uint2(lo, hi);
      }
      {
        int c = q ^ ((x >> 1) & 3);
        bf16x8 ap = *(const bf16x8*)((const char*)PW + x * 64 + c * 16);
#pragma unroll
        for (int cf = 0; cf < 16; ++cf) {
          bf16x8 bg = *(const bf16x8*)(GT + (cf * 16 + x) * 32 + ((q ^ sgx) * 8));
          acc[cf] = __builtin_amdgcn_mfma_f32_16x16x32_bf16(ap, bg, acc[cf], 0, 0, 0);
        }
      }
    }
    if (jt + 1 < NT) ATTN_WRITE(cur ^ 1);
    __syncthreads();
    cur ^= 1;
  }
  // store bf16: D[i=4q+r][cc=x]; om is [cc][i]
#pragma unroll
  for (int cf = 0; cf < 16; ++cf) {
    __align__(8) short pv[4];
#pragma unroll
    for (int j = 0; j < 4; ++j) pv[j] = (short)f2bf(acc[cf][j]);
    size_t o = (size_t)(cf * 16 + x) * NPOS + i0 + w * 16 + 4 * q;
    *(uint2*)(om + o) = *(const uint2*)pv;
  }
#undef ATTN_LOAD
#undef ATTN_WRITE
}

extern "C" void kernel_launch(void* const* d_in, const int* in_sizes, int n_in,
                              void* d_out, int out_size, void* d_ws, size_t ws_size,
                              hipStream_t stream) {
  (void)in_sizes; (void)n_in; (void)out_size; (void)ws_size;
  const float* x0      = (const float*)d_in[0];
  const float* x       = (const float*)d_in[1];
  const float* x_dsm   = (const float*)d_in[2];
  const float* w_phi   = (const float*)d_in[3];
  const float* w_theta = (const float*)d_in[4];
  const float* w_g     = (const float*)d_in[5];
  const float* w_mask  = (const float*)d_in[6];
  float* outp = (float*)d_out;

  short* sp = (short*)d_ws;
  short* wb_phi   = sp; sp += 32768;
  short* wb_theta = sp; sp += 32768;
  short* wb_g     = sp; sp += 131072;
  short* wb_mask  = sp; sp += 131072;
  short* xT   = sp; sp += (size_t)NB * NPOS * NC;          // 8MB
  short* xdT  = sp; sp += (size_t)NB * NPOS * NC;          // 8MB
  short* x0T  = sp; sp += (size_t)NB * NPOS * NC2;         // 16MB
  short* phiB   = sp; sp += (size_t)NB * NPOS * NCI;       // 4MB
  short* thetaB = sp; sp += (size_t)NB * NPOS * NCI;       // 4MB
  short* gBuf   = sp; sp += (size_t)NB * NC * NPOS;        // 8MB
  float* linv = (float*)sp; sp += 2 * (size_t)NB * NPOS;
  float* plsum = (float*)sp;                               // [b][ISPLIT][NPOS]
  short* omidP = xT;       // 4 bf16 partials x 8MB = 32MB, aliases dead xT/xdT/x0T
  short* omidT = phiB;     // 8MB bf16 [b][p][cc], aliases dead phiB/thetaB

  k_cast4<<<dim3(1280), 256, 0, stream>>>(w_phi, wb_phi, 32768,
                                          w_theta, wb_theta, 32768,
                                          w_g, wb_g, 131072,
                                          w_mask, wb_mask, 131072);

  k_tcast_all<<<dim3(64, 16, NB), 256, 0, stream>>>(x, x_dsm, x0, xT, xdT, x0T);

  k_gemm<true, false><<<dim3(64, 2, NB), 256, 0, stream>>>(
      wb_phi, xT, phiB, nullptr, NC, NCI, 0, (size_t)NPOS * NC, (size_t)NPOS * NCI);
  k_gemm<true, false><<<dim3(64, 2, NB), 256, 0, stream>>>(
      wb_theta, xdT, thetaB, nullptr, NC, NCI, 0, (size_t)NPOS * NC, (size_t)NPOS * NCI);
  k_gemm<true, false><<<dim3(4, 64, NB), 256, 0, stream>>>(
      x0T, wb_g, gBuf, nullptr, NC2, NPOS, (size_t)NPOS * NC2, 0, (size_t)NC * NPOS);

  k_lsum<<<dim3(NPOS / 64, ISPLIT, NB), 256, 0, stream>>>(phiB, thetaB, plsum);
  k_lcomb<<<dim3(NB * NPOS / 256), 256, 0, stream>>>(plsum, linv);
  k_scale_g<<<dim3(2048), 256, 0, stream>>>(gBuf, linv);

  k_attn<<<dim3(64, 4, NB), 256, 0, stream>>>(phiB, thetaB, gBuf, omidP);

  k_tcast4<<<dim3(64, 4, NB), 256, 0, stream>>>(omidP, omidT);

  k_gemm<false, true><<<dim3(8, 64, NB), 256, 0, stream>>>(
      omidT, wb_mask, outp, x0, NC, NPOS, (size_t)NPOS * NC, 0, (size_t)NC2 * NPOS);
}

// Round 14
// 236.911 us; speedup vs baseline: 1.9163x; 1.0633x over previous
//
#include <hip/hip_runtime.h>
#include <math.h>

#define NB 4
#define NC 256
#define NCI 128
#define NC2 512
#define NPOS 4096
#define ISPLIT 8

using bf16x8 = __attribute__((ext_vector_type(8))) short;
using f32x4  = __attribute__((ext_vector_type(4))) float;
using f32x16 = __attribute__((ext_vector_type(16))) float;

__device__ inline unsigned short f2bf(float f) {
  unsigned int u = __float_as_uint(f);
  u = (u + 0x7fffu + ((u >> 16) & 1u)) >> 16;
  return (unsigned short)u;
}
__device__ inline float bf2f(short s) {
  return __uint_as_float(((unsigned int)(unsigned short)s) << 16);
}

// ---------------- cast 4 weight tensors fp32 -> bf16 ----------------
__global__ void k_cast4(const float* __restrict__ s0, short* __restrict__ d0, int n0,
                        const float* __restrict__ s1, short* __restrict__ d1, int n1,
                        const float* __restrict__ s2, short* __restrict__ d2, int n2,
                        const float* __restrict__ s3, short* __restrict__ d3, int n3) {
  int i = blockIdx.x * 256 + threadIdx.x;
  if (i < n0) { d0[i] = (short)f2bf(s0[i]); return; } i -= n0;
  if (i < n1) { d1[i] = (short)f2bf(s1[i]); return; } i -= n1;
  if (i < n2) { d2[i] = (short)f2bf(s2[i]); return; } i -= n2;
  if (i < n3) { d3[i] = (short)f2bf(s3[i]); }
}

// ---------------- fused transpose-cast for x, x_dsm, x0 ----------------
__global__ __launch_bounds__(256) void k_tcast_all(
    const float* __restrict__ x, const float* __restrict__ xdsm,
    const float* __restrict__ x0, short* __restrict__ xT,
    short* __restrict__ xdT, short* __restrict__ x0T) {
  __shared__ float t[64][65];
  const int tid = threadIdx.x;
  const int y = blockIdx.y, c0 = blockIdx.x * 64, b = blockIdx.z;
  const float* in; short* out; int R, r0;
  if (y < 4)      { in = x;    out = xT;  R = NC;  r0 = y * 64; }
  else if (y < 8) { in = xdsm; out = xdT; R = NC;  r0 = (y - 4) * 64; }
  else            { in = x0;   out = x0T; R = NC2; r0 = (y - 8) * 64; }
  const size_t inBs = (size_t)R * NPOS, outBs = (size_t)NPOS * R;
  {
    int r = tid >> 2, cc = (tid & 3) * 16;
    const float* ib = in + (size_t)b * inBs + (size_t)(r0 + r) * NPOS + c0 + cc;
#pragma unroll
    for (int i = 0; i < 4; ++i) {
      float4 v = *(const float4*)(ib + i * 4);
      t[r][cc + i * 4 + 0] = v.x; t[r][cc + i * 4 + 1] = v.y;
      t[r][cc + i * 4 + 2] = v.z; t[r][cc + i * 4 + 3] = v.w;
    }
  }
  __syncthreads();
  {
    int c = tid >> 2, rr = (tid & 3) * 16;
    __align__(16) short v[16];
#pragma unroll
    for (int i = 0; i < 16; ++i) v[i] = (short)f2bf(t[rr + i][c]);
    short* ob = out + (size_t)b * outBs + (size_t)(c0 + c) * R + r0 + rr;
    *(int4*)(ob) = *(const int4*)(v);
    *(int4*)(ob + 8) = *(const int4*)(v + 8);
  }
}

// ---------------- sum 4 bf16 partials [p][b][cc][i] -> transpose [b][i][cc] bf16
__global__ __launch_bounds__(256) void k_tcast4(
    const short* __restrict__ inP, short* __restrict__ out) {
  __shared__ float t[64][65];
  const int tid = threadIdx.x;
  const int r0 = blockIdx.y * 64, c0 = blockIdx.x * 64, b = blockIdx.z;
  {
    int r = tid >> 2, cc = (tid & 3) * 16;
    float tacc[16] = {};
#pragma unroll
    for (int p = 0; p < 4; ++p) {
      const short* ib = inP + ((size_t)p * NB + b) * NC * NPOS +
                        (size_t)(r0 + r) * NPOS + c0 + cc;
      bf16x8 a = *(const bf16x8*)(ib);
      bf16x8 a2 = *(const bf16x8*)(ib + 8);
#pragma unroll
      for (int i = 0; i < 8; ++i) { tacc[i] += bf2f(a[i]); tacc[8 + i] += bf2f(a2[i]); }
    }
#pragma unroll
    for (int i = 0; i < 16; ++i) t[r][cc + i] = tacc[i];
  }
  __syncthreads();
  {
    int c = tid >> 2, rr = (tid & 3) * 16;
    __align__(16) short v[16];
#pragma unroll
    for (int i = 0; i < 16; ++i) v[i] = (short)f2bf(t[rr + i][c]);
    short* ob = out + (size_t)b * (size_t)NPOS * NC + (size_t)(c0 + c) * NC + r0 + rr;
    *(int4*)(ob) = *(const int4*)(v);
    *(int4*)(ob + 8) = *(const int4*)(v + 8);
  }
}

// ---------------- generic bf16 MFMA GEMM ----------------
template<bool OUT_BF16, bool HAS_RES>
__global__ __launch_bounds__(256, 2) void k_gemm(
    const short* __restrict__ A, const short* __restrict__ B,
    void* __restrict__ outv, const float* __restrict__ res,
    int K, int sN, size_t aBs, size_t bBs, size_t oBs) {
  __shared__ short As[2][64 * 64];
  __shared__ short Bs_[2][64 * 64];
  const int tid = threadIdx.x, lane = tid & 63, w = tid >> 6;
  const int x = lane & 15, q = lane >> 4;
  const int wm = (w & 1) * 32, wn = (w >> 1) * 32;
  const int n0 = blockIdx.x * 64, m0 = blockIdx.y * 64, b = blockIdx.z;
  const short* Ab = A + (size_t)b * aBs + (size_t)m0 * K;
  const short* Bb = B + (size_t)b * bBs + (size_t)n0 * K;
  const int r = tid >> 2, cth = tid & 3;
  f32x4 acc[2][2];
  acc[0][0] = acc[0][1] = acc[1][0] = acc[1][1] = (f32x4){0.f, 0.f, 0.f, 0.f};
  int4 ra[2], rb[2];
  const int NK = K >> 6;
#define GLOAD(kt)                                                              \
  { _Pragma("unroll") for (int i = 0; i < 2; ++i) {                            \
      ra[i] = *(const int4*)(Ab + (size_t)r * K + (kt) * 64 + (cth + i * 4) * 8); \
      rb[i] = *(const int4*)(Bb + (size_t)r * K + (kt) * 64 + (cth + i * 4) * 8); } }
#define GWRITE(buf)                                                            \
  { _Pragma("unroll") for (int i = 0; i < 2; ++i) {                            \
      *(int4*)(&As[buf][r * 64 + (((cth + i * 4) ^ (r & 7)) * 8)]) = ra[i];    \
      *(int4*)(&Bs_[buf][r * 64 + (((cth + i * 4) ^ (r & 7)) * 8)]) = rb[i]; } }
  GLOAD(0); GWRITE(0); __syncthreads();
  int cur = 0;
  for (int kt = 0; kt < NK; ++kt) {
    if (kt + 1 < NK) GLOAD(kt + 1);
    bf16x8 af[2][2], bfr[2][2];
#pragma unroll
    for (int ms = 0; ms < 2; ++ms) {
      int rowm = wm + ms * 16 + x;
#pragma unroll
      for (int ks = 0; ks < 2; ++ks)
        af[ms][ks] = *(const bf16x8*)(&As[cur][rowm * 64 + (((ks * 4 + q) ^ (rowm & 7)) * 8)]);
    }
#pragma unroll
    for (int ns = 0; ns < 2; ++ns) {
      int rown = wn + ns * 16 + x;
#pragma unroll
      for (int ks = 0; ks < 2; ++ks)
        bfr[ns][ks] = *(const bf16x8*)(&Bs_[cur][rown * 64 + (((ks * 4 + q) ^ (rown & 7)) * 8)]);
    }
#pragma unroll
    for (int ms = 0; ms < 2; ++ms)
#pragma unroll
      for (int ns = 0; ns < 2; ++ns)
#pragma unroll
        for (int ks = 0; ks < 2; ++ks)
          acc[ms][ns] = __builtin_amdgcn_mfma_f32_16x16x32_bf16(
              af[ms][ks], bfr[ns][ks], acc[ms][ns], 0, 0, 0);
    if (kt + 1 < NK) GWRITE(cur ^ 1);
    __syncthreads();
    cur ^= 1;
  }
#pragma unroll
  for (int ms = 0; ms < 2; ++ms)
#pragma unroll
    for (int ns = 0; ns < 2; ++ns) {
      int n = n0 + wn + ns * 16 + x;
      int m = m0 + wm + ms * 16 + q * 4;
      size_t off = (size_t)b * oBs + (size_t)n * sN + m;
      if (OUT_BF16) {
        __align__(8) short pv[4];
#pragma unroll
        for (int j = 0; j < 4; ++j) pv[j] = (short)f2bf(acc[ms][ns][j]);
        *(uint2*)((short*)outv + off) = *(const uint2*)pv;
      } else {
        float4 v = {acc[ms][ns][0], acc[ms][ns][1], acc[ms][ns][2], acc[ms][ns][3]};
        if (HAS_RES) {
          float4 rv = *(const float4*)(res + off);
          v.x += rv.x; v.y += rv.y; v.z += rv.z; v.w += rv.w;
        }
        *(float4*)((float*)outv + off) = v;
      }
    }
#undef GLOAD
#undef GWRITE
}

// ---------------- partial l[j]: plsum[b][iy][j] = sum_{i in chunk} exp(s[i][j]) ----
__global__ __launch_bounds__(256, 4) void k_lsum(
    const short* __restrict__ phiB, const short* __restrict__ thetaB,
    float* __restrict__ plsum) {
  __shared__ short thT[2][64 * 128];
  const int tid = threadIdx.x, lane = tid & 63, w = tid >> 6;
  const int x = lane & 15, q = lane >> 4;
  const int j0 = blockIdx.x * 64, iy = blockIdx.y, b = blockIdx.z;
  const short* phb = phiB + (size_t)b * NPOS * NCI;
  const short* thb = thetaB + (size_t)b * NPOS * NCI + (size_t)iy * (NPOS / ISPLIT) * NCI;
  bf16x8 af[4];
  {
    const short* pr = phb + (size_t)(j0 + w * 16 + x) * NCI;
#pragma unroll
    for (int kk = 0; kk < 4; ++kk) af[kk] = *(const bf16x8*)(pr + kk * 32 + q * 8);
  }
  float lsum[4] = {0.f, 0.f, 0.f, 0.f};
  int4 rt[4];
  const int NIT = NPOS / ISPLIT / 64;   // 8
#define LSUM_LOAD(it)                                                         \
  { _Pragma("unroll") for (int r = 0; r < 4; ++r) {                           \
      int s = tid + r * 256; int row = s >> 4, c = s & 15;                    \
      rt[r] = *(const int4*)(thb + (size_t)((it) * 64 + row) * NCI + c * 8); } }
#define LSUM_WRITE(buf)                                                       \
  { _Pragma("unroll") for (int r = 0; r < 4; ++r) {                           \
      int s = tid + r * 256; int row = s >> 4, c = s & 15;                    \
      *(int4*)(&thT[buf][row * 128 + ((c ^ (row & 7)) * 8)]) = rt[r]; } }
  LSUM_LOAD(0); LSUM_WRITE(0); __syncthreads();
  int cur = 0;
  for (int it = 0; it < NIT; ++it) {
    if (it + 1 < NIT) LSUM_LOAD(it + 1);
#pragma unroll
    for (int ii = 0; ii < 4; ++ii) {
      f32x4 s = {0.f, 0.f, 0.f, 0.f};
      int row = ii * 16 + x;
      int sw = row & 7;
#pragma unroll
      for (int kk = 0; kk < 4; ++kk) {
        bf16x8 bfv = *(const bf16x8*)(&thT[cur][row * 128 + (((kk * 4 + q) ^ sw) * 8)]);
        s = __builtin_amdgcn_mfma_f32_16x16x32_bf16(af[kk], bfv, s, 0, 0, 0);
      }
#pragma unroll
      for (int r = 0; r < 4; ++r) lsum[r] += __expf(s[r]);
    }
    if (it + 1 < NIT) LSUM_WRITE(cur ^ 1);
    __syncthreads();
    cur ^= 1;
  }
#pragma unroll
  for (int m = 1; m < 16; m <<= 1)
#pragma unroll
    for (int r = 0; r < 4; ++r) lsum[r] += __shfl_xor(lsum[r], m);
  if (x == 0) {
#pragma unroll
    for (int r = 0; r < 4; ++r)
      plsum[((size_t)(b * ISPLIT + iy) << 12) + j0 + w * 16 + 4 * q + r] = lsum[r];
  }
#undef LSUM_LOAD
#undef LSUM_WRITE
}

// ---------------- combine partials -> linv ----------------
__global__ void k_lcomb(const float* __restrict__ plsum, float* __restrict__ linv) {
  int i = blockIdx.x * 256 + threadIdx.x;   // NB*NPOS
  int b = i >> 12, j = i & (NPOS - 1);
  float s = 0.f;
#pragma unroll
  for (int t = 0; t < ISPLIT; ++t) s += plsum[((size_t)(b * ISPLIT + t) << 12) + j];
  linv[i] = 1.0f / s;
}

// ---------------- fold linv into g: gB[cc][p] *= linv[p] ----------------
__global__ void k_scale_g(short* __restrict__ gB, const float* __restrict__ linv) {
  size_t e = ((size_t)blockIdx.x * 256 + threadIdx.x) * 8;
  int b = (int)(e >> 20);
  int p = (int)(e & (NPOS - 1));
  __align__(16) short v[8];
  *(int4*)v = *(const int4*)(gB + e);
  const float* lv = linv + ((size_t)b << 12) + p;
#pragma unroll
  for (int k = 0; k < 8; ++k) v[k] = (short)f2bf(bf2f(v[k]) * lv[k]);
  *(int4*)(gB + e) = *(const int4*)v;
}

// ---------------- attention, 32x32x16 MFMA ----------------
// Block: 128 i rows (wave w owns i = i0+w*32+(lane&31)); j-quarter, tiles of 32 j.
// S^T = mfma32(A=phi, B=theta-in-regs) -> per-wave pT; PV = mfma32(A=pT, B=gT).
// omidP[jq][b][cc][i] bf16.
__global__ __launch_bounds__(256, 2) void k_attn(
    const short* __restrict__ phiB, const short* __restrict__ thetaB,
    const short* __restrict__ gB, short* __restrict__ omidP) {
  __shared__ short phiT[2][32 * 128];   // 8KB each, chunk-swizzled ^(row&7)
  __shared__ short gT[2][256 * 32];     // 16KB each, slot-swizzled ^((row>>1)&3)
  __shared__ short pT[4][32 * 32];      // 2KB per wave, slot-swizzled
  const int tid = threadIdx.x, lane = tid & 63, w = tid >> 6;
  const int il = lane & 31, h = lane >> 5;
  const int key = (il >> 1) & 3;        // 16B-slot swizzle key (row = il)
  const int i0 = blockIdx.x * 128, jq = blockIdx.y, b = blockIdx.z;
  const short* phb = phiB + (size_t)b * NPOS * NCI;
  const short* thb = thetaB + (size_t)b * NPOS * NCI;
  const short* gb = gB + (size_t)b * NC * NPOS;
  short* om = omidP + ((size_t)(jq * NB + b)) * NC * NPOS;

  // theta B-frags: col i = i0 + w*32 + il, k-chunk kk*16 + h*8
  bf16x8 tf[8];
  {
    const short* tr = thb + (size_t)(i0 + w * 32 + il) * NCI;
#pragma unroll
    for (int kk = 0; kk < 8; ++kk) tf[kk] = *(const bf16x8*)(tr + kk * 16 + h * 8);
  }
  f32x16 acc[8];
#pragma unroll
  for (int i = 0; i < 8; ++i)
#pragma unroll
    for (int r = 0; r < 16; ++r) acc[i][r] = 0.f;

  int4 rphi[2], rg[4];
  const int NT = 32;                    // 32 j-tiles of 32 per quarter
  const int jbase = jq * 32;
#define ATTN_LOAD(jt)                                                          \
  { _Pragma("unroll") for (int r = 0; r < 2; ++r) {                            \
      int s = tid + r * 256; int row = s >> 4, c = s & 15;                     \
      rphi[r] = *(const int4*)(phb + (size_t)((jbase + (jt)) * 32 + row) * NCI + c * 8); } \
    _Pragma("unroll") for (int r = 0; r < 4; ++r) {                            \
      int s = tid + r * 256; int cc = s >> 2, c4 = s & 3;                      \
      rg[r] = *(const int4*)(gb + (size_t)cc * NPOS + (jbase + (jt)) * 32 + c4 * 8); } }
#define ATTN_WRITE(buf)                                                        \
  { _Pragma("unroll") for (int r = 0; r < 2; ++r) {                            \
      int s = tid + r * 256; int row = s >> 4, c = s & 15;                     \
      *(int4*)(&phiT[buf][row * 128 + ((c ^ (row & 7)) * 8)]) = rphi[r]; }     \
    _Pragma("unroll") for (int r = 0; r < 4; ++r) {                            \
      int s = tid + r * 256; int cc = s >> 2, c4 = s & 3;                      \
      *(int4*)(&gT[buf][cc * 32 + ((c4 ^ ((cc >> 1) & 3)) * 8)]) = rg[r]; } }
  ATTN_LOAD(0); ATTN_WRITE(0); __syncthreads();
  int cur = 0;
  for (int jt = 0; jt < NT; ++jt) {
    if (jt + 1 < NT) ATTN_LOAD(jt + 1);
    {
      const short* PH = &phiT[cur][0];
      short* PW = &pT[w][0];
      // ---- S^T: 32 j x 32 i, K=128 via 8 mfma 32x32x16 ----
      f32x16 s16;
#pragma unroll
      for (int r = 0; r < 16; ++r) s16[r] = 0.f;
      const int swp = il & 7;           // phi chunk swizzle (row = j = il)
#pragma unroll
      for (int kk = 0; kk < 8; ++kk) {
        bf16x8 a = *(const bf16x8*)(PH + il * 128 + (((2 * kk + h) ^ swp) * 8));
        s16 = __builtin_amdgcn_mfma_f32_32x32x16_bf16(a, tf[kk], s16, 0, 0, 0);
      }
      // lane holds S^T[j=(r&3)+8*(r>>2)+4h][i = i0+w*32+il]; P = exp(S)
      // write P[i=il][j] : slot g2 (j in [8g2,8g2+8)), 8B half h
#pragma unroll
      for (int g2 = 0; g2 < 4; ++g2) {
        unsigned short p0 = f2bf(__expf(s16[4 * g2 + 0]));
        unsigned short p1 = f2bf(__expf(s16[4 * g2 + 1]));
        unsigned short p2 = f2bf(__expf(s16[4 * g2 + 2]));
        unsigned short p3 = f2bf(__expf(s16[4 * g2 + 3]));
        unsigned int lo = (unsigned int)p0 | ((unsigned int)p1 << 16);
        unsigned int hi2 = (unsigned int)p2 | ((unsigned int)p3 << 16);
        *(uint2*)(PW + il * 32 + ((g2 ^ key) * 8) + 4 * h) = make_uint2(lo, hi2);
      }
      // ---- PV: wave's 32 i x all 256 cc ----
      const short* GT = &gT[cur][0];
      bf16x8 pa[2];
#pragma unroll
      for (int jh2 = 0; jh2 < 2; ++jh2)
        pa[jh2] = *(const bf16x8*)(PW + il * 32 + (((2 * jh2 + h) ^ key) * 8));
#pragma unroll
      for (int ct = 0; ct < 8; ++ct) {
#pragma unroll
        for (int jh2 = 0; jh2 < 2; ++jh2) {
          bf16x8 bg = *(const bf16x8*)(GT + (ct * 32 + il) * 32 + (((2 * jh2 + h) ^ key) * 8));
          acc[ct] = __builtin_amdgcn_mfma_f32_32x32x16_bf16(pa[jh2], bg, acc[ct], 0, 0, 0);
        }
      }
    }
    if (jt + 1 < NT) ATTN_WRITE(cur ^ 1);
    __syncthreads();
    cur ^= 1;
  }
  // store bf16: acc[ct]: cc = ct*32+il, i = i0+w*32 + (r&3)+8*(r>>2)+4h
#pragma unroll
  for (int ct = 0; ct < 8; ++ct)
#pragma unroll
    for (int g2 = 0; g2 < 4; ++g2) {
      __align__(8) short pv[4];
#pragma unroll
      for (int e = 0; e < 4; ++e) pv[e] = (short)f2bf(acc[ct][4 * g2 + e]);
      size_t o = (size_t)(ct * 32 + il) * NPOS + i0 + w * 32 + 8 * g2 + 4 * h;
      *(uint2*)(om + o) = *(const uint2*)pv;
    }
#undef ATTN_LOAD
#undef ATTN_WRITE
}

extern "C" void kernel_launch(void* const* d_in, const int* in_sizes, int n_in,
                              void* d_out, int out_size, void* d_ws, size_t ws_size,
                              hipStream_t stream) {
  (void)in_sizes; (void)n_in; (void)out_size; (void)ws_size;
  const float* x0      = (const float*)d_in[0];
  const float* x       = (const float*)d_in[1];
  const float* x_dsm   = (const float*)d_in[2];
  const float* w_phi   = (const float*)d_in[3];
  const float* w_theta = (const float*)d_in[4];
  const float* w_g     = (const float*)d_in[5];
  const float* w_mask  = (const float*)d_in[6];
  float* outp = (float*)d_out;

  short* sp = (short*)d_ws;
  short* wb_phi   = sp; sp += 32768;
  short* wb_theta = sp; sp += 32768;
  short* wb_g     = sp; sp += 131072;
  short* wb_mask  = sp; sp += 131072;
  short* xT   = sp; sp += (size_t)NB * NPOS * NC;          // 8MB
  short* xdT  = sp; sp += (size_t)NB * NPOS * NC;          // 8MB
  short* x0T  = sp; sp += (size_t)NB * NPOS * NC2;         // 16MB
  short* phiB   = sp; sp += (size_t)NB * NPOS * NCI;       // 4MB
  short* thetaB = sp; sp += (size_t)NB * NPOS * NCI;       // 4MB
  short* gBuf   = sp; sp += (size_t)NB * NC * NPOS;        // 8MB
  float* linv = (float*)sp; sp += 2 * (size_t)NB * NPOS;
  float* plsum = (float*)sp;                               // [b][ISPLIT][NPOS]
  short* omidP = xT;       // 4 bf16 partials x 8MB = 32MB, aliases dead xT/xdT/x0T
  short* omidT = phiB;     // 8MB bf16 [b][p][cc], aliases dead phiB/thetaB

  k_cast4<<<dim3(1280), 256, 0, stream>>>(w_phi, wb_phi, 32768,
                                          w_theta, wb_theta, 32768,
                                          w_g, wb_g, 131072,
                                          w_mask, wb_mask, 131072);

  k_tcast_all<<<dim3(64, 16, NB), 256, 0, stream>>>(x, x_dsm, x0, xT, xdT, x0T);

  k_gemm<true, false><<<dim3(64, 2, NB), 256, 0, stream>>>(
      wb_phi, xT, phiB, nullptr, NC, NCI, 0, (size_t)NPOS * NC, (size_t)NPOS * NCI);
  k_gemm<true, false><<<dim3(64, 2, NB), 256, 0, stream>>>(
      wb_theta, xdT, thetaB, nullptr, NC, NCI, 0, (size_t)NPOS * NC, (size_t)NPOS * NCI);
  k_gemm<true, false><<<dim3(4, 64, NB), 256, 0, stream>>>(
      x0T, wb_g, gBuf, nullptr, NC2, NPOS, (size_t)NPOS * NC2, 0, (size_t)NC * NPOS);

  k_lsum<<<dim3(NPOS / 64, ISPLIT, NB), 256, 0, stream>>>(phiB, thetaB, plsum);
  k_lcomb<<<dim3(NB * NPOS / 256), 256, 0, stream>>>(plsum, linv);
  k_scale_g<<<dim3(2048), 256, 0, stream>>>(gBuf, linv);

  k_attn<<<dim3(NPOS / 128, 4, NB), 256, 0, stream>>>(phiB, thetaB, gBuf, omidP);

  k_tcast4<<<dim3(64, 4, NB), 256, 0, stream>>>(omidP, omidT);

  k_gemm<false, true><<<dim3(8, 64, NB), 256, 0, stream>>>(
      omidT, wb_mask, outp, x0, NC, NPOS, (size_t)NPOS * NC, 0, (size_t)NC2 * NPOS);
}

// Round 19
// 231.730 us; speedup vs baseline: 1.9592x; 1.0224x over previous
//
#include <hip/hip_runtime.h>
#include <math.h>

#define NB 4
#define NC 256
#define NCI 128
#define NC2 512
#define NPOS 4096
#define ISPLIT 8

using bf16x8 = __attribute__((ext_vector_type(8))) short;
using f32x4  = __attribute__((ext_vector_type(4))) float;
using f32x16 = __attribute__((ext_vector_type(16))) float;

__device__ inline unsigned short f2bf(float f) {
  unsigned int u = __float_as_uint(f);
  u = (u + 0x7fffu + ((u >> 16) & 1u)) >> 16;
  return (unsigned short)u;
}
__device__ inline float bf2f(short s) {
  return __uint_as_float(((unsigned int)(unsigned short)s) << 16);
}

// ---------------- cast 4 weight tensors fp32 -> bf16 ----------------
__global__ void k_cast4(const float* __restrict__ s0, short* __restrict__ d0, int n0,
                        const float* __restrict__ s1, short* __restrict__ d1, int n1,
                        const float* __restrict__ s2, short* __restrict__ d2, int n2,
                        const float* __restrict__ s3, short* __restrict__ d3, int n3) {
  int i = blockIdx.x * 256 + threadIdx.x;
  if (i < n0) { d0[i] = (short)f2bf(s0[i]); return; } i -= n0;
  if (i < n1) { d1[i] = (short)f2bf(s1[i]); return; } i -= n1;
  if (i < n2) { d2[i] = (short)f2bf(s2[i]); return; } i -= n2;
  if (i < n3) { d3[i] = (short)f2bf(s3[i]); }
}

// ---------------- fused transpose-cast for x, x_dsm, x0 ----------------
__global__ __launch_bounds__(256) void k_tcast_all(
    const float* __restrict__ x, const float* __restrict__ xdsm,
    const float* __restrict__ x0, short* __restrict__ xT,
    short* __restrict__ xdT, short* __restrict__ x0T) {
  __shared__ float t[64][65];
  const int tid = threadIdx.x;
  const int y = blockIdx.y, c0 = blockIdx.x * 64, b = blockIdx.z;
  const float* in; short* out; int R, r0;
  if (y < 4)      { in = x;    out = xT;  R = NC;  r0 = y * 64; }
  else if (y < 8) { in = xdsm; out = xdT; R = NC;  r0 = (y - 4) * 64; }
  else            { in = x0;   out = x0T; R = NC2; r0 = (y - 8) * 64; }
  const size_t inBs = (size_t)R * NPOS, outBs = (size_t)NPOS * R;
  {
    int r = tid >> 2, cc = (tid & 3) * 16;
    const float* ib = in + (size_t)b * inBs + (size_t)(r0 + r) * NPOS + c0 + cc;
#pragma unroll
    for (int i = 0; i < 4; ++i) {
      float4 v = *(const float4*)(ib + i * 4);
      t[r][cc + i * 4 + 0] = v.x; t[r][cc + i * 4 + 1] = v.y;
      t[r][cc + i * 4 + 2] = v.z; t[r][cc + i * 4 + 3] = v.w;
    }
  }
  __syncthreads();
  {
    int c = tid >> 2, rr = (tid & 3) * 16;
    __align__(16) short v[16];
#pragma unroll
    for (int i = 0; i < 16; ++i) v[i] = (short)f2bf(t[rr + i][c]);
    short* ob = out + (size_t)b * outBs + (size_t)(c0 + c) * R + r0 + rr;
    *(int4*)(ob) = *(const int4*)(v);
    *(int4*)(ob + 8) = *(const int4*)(v + 8);
  }
}

// ---------------- sum 4 bf16 partials [p][b][cc][i] -> transpose [b][i][cc] bf16
__global__ __launch_bounds__(256) void k_tcast4(
    const short* __restrict__ inP, short* __restrict__ out) {
  __shared__ float t[64][65];
  const int tid = threadIdx.x;
  const int r0 = blockIdx.y * 64, c0 = blockIdx.x * 64, b = blockIdx.z;
  {
    int r = tid >> 2, cc = (tid & 3) * 16;
    float tacc[16] = {};
#pragma unroll
    for (int p = 0; p < 4; ++p) {
      const short* ib = inP + ((size_t)p * NB + b) * NC * NPOS +
                        (size_t)(r0 + r) * NPOS + c0 + cc;
      bf16x8 a = *(const bf16x8*)(ib);
      bf16x8 a2 = *(const bf16x8*)(ib + 8);
#pragma unroll
      for (int i = 0; i < 8; ++i) { tacc[i] += bf2f(a[i]); tacc[8 + i] += bf2f(a2[i]); }
    }
#pragma unroll
    for (int i = 0; i < 16; ++i) t[r][cc + i] = tacc[i];
  }
  __syncthreads();
  {
    int c = tid >> 2, rr = (tid & 3) * 16;
    __align__(16) short v[16];
#pragma unroll
    for (int i = 0; i < 16; ++i) v[i] = (short)f2bf(t[rr + i][c]);
    short* ob = out + (size_t)b * (size_t)NPOS * NC + (size_t)(c0 + c) * NC + r0 + rr;
    *(int4*)(ob) = *(const int4*)(v);
    *(int4*)(ob + 8) = *(const int4*)(v + 8);
  }
}

// ---------------- generic bf16 MFMA GEMM ----------------
template<bool OUT_BF16, bool HAS_RES>
__global__ __launch_bounds__(256, 2) void k_gemm(
    const short* __restrict__ A, const short* __restrict__ B,
    void* __restrict__ outv, const float* __restrict__ res,
    int K, int sN, size_t aBs, size_t bBs, size_t oBs) {
  __shared__ short As[2][64 * 64];
  __shared__ short Bs_[2][64 * 64];
  const int tid = threadIdx.x, lane = tid & 63, w = tid >> 6;
  const int x = lane & 15, q = lane >> 4;
  const int wm = (w & 1) * 32, wn = (w >> 1) * 32;
  const int n0 = blockIdx.x * 64, m0 = blockIdx.y * 64, b = blockIdx.z;
  const short* Ab = A + (size_t)b * aBs + (size_t)m0 * K;
  const short* Bb = B + (size_t)b * bBs + (size_t)n0 * K;
  const int r = tid >> 2, cth = tid & 3;
  f32x4 acc[2][2];
  acc[0][0] = acc[0][1] = acc[1][0] = acc[1][1] = (f32x4){0.f, 0.f, 0.f, 0.f};
  int4 ra[2], rb[2];
  const int NK = K >> 6;
#define GLOAD(kt)                                                              \
  { _Pragma("unroll") for (int i = 0; i < 2; ++i) {                            \
      ra[i] = *(const int4*)(Ab + (size_t)r * K + (kt) * 64 + (cth + i * 4) * 8); \
      rb[i] = *(const int4*)(Bb + (size_t)r * K + (kt) * 64 + (cth + i * 4) * 8); } }
#define GWRITE(buf)                                                            \
  { _Pragma("unroll") for (int i = 0; i < 2; ++i) {                            \
      *(int4*)(&As[buf][r * 64 + (((cth + i * 4) ^ (r & 7)) * 8)]) = ra[i];    \
      *(int4*)(&Bs_[buf][r * 64 + (((cth + i * 4) ^ (r & 7)) * 8)]) = rb[i]; } }
  GLOAD(0); GWRITE(0); __syncthreads();
  int cur = 0;
  for (int kt = 0; kt < NK; ++kt) {
    if (kt + 1 < NK) GLOAD(kt + 1);
    bf16x8 af[2][2], bfr[2][2];
#pragma unroll
    for (int ms = 0; ms < 2; ++ms) {
      int rowm = wm + ms * 16 + x;
#pragma unroll
      for (int ks = 0; ks < 2; ++ks)
        af[ms][ks] = *(const bf16x8*)(&As[cur][rowm * 64 + (((ks * 4 + q) ^ (rowm & 7)) * 8)]);
    }
#pragma unroll
    for (int ns = 0; ns < 2; ++ns) {
      int rown = wn + ns * 16 + x;
#pragma unroll
      for (int ks = 0; ks < 2; ++ks)
        bfr[ns][ks] = *(const bf16x8*)(&Bs_[cur][rown * 64 + (((ks * 4 + q) ^ (rown & 7)) * 8)]);
    }
#pragma unroll
    for (int ms = 0; ms < 2; ++ms)
#pragma unroll
      for (int ns = 0; ns < 2; ++ns)
#pragma unroll
        for (int ks = 0; ks < 2; ++ks)
          acc[ms][ns] = __builtin_amdgcn_mfma_f32_16x16x32_bf16(
              af[ms][ks], bfr[ns][ks], acc[ms][ns], 0, 0, 0);
    if (kt + 1 < NK) GWRITE(cur ^ 1);
    __syncthreads();
    cur ^= 1;
  }
#pragma unroll
  for (int ms = 0; ms < 2; ++ms)
#pragma unroll
    for (int ns = 0; ns < 2; ++ns) {
      int n = n0 + wn + ns * 16 + x;
      int m = m0 + wm + ms * 16 + q * 4;
      size_t off = (size_t)b * oBs + (size_t)n * sN + m;
      if (OUT_BF16) {
        __align__(8) short pv[4];
#pragma unroll
        for (int j = 0; j < 4; ++j) pv[j] = (short)f2bf(acc[ms][ns][j]);
        *(uint2*)((short*)outv + off) = *(const uint2*)pv;
      } else {
        float4 v = {acc[ms][ns][0], acc[ms][ns][1], acc[ms][ns][2], acc[ms][ns][3]};
        if (HAS_RES) {
          float4 rv = *(const float4*)(res + off);
          v.x += rv.x; v.y += rv.y; v.z += rv.z; v.w += rv.w;
        }
        *(float4*)((float*)outv + off) = v;
      }
    }
#undef GLOAD
#undef GWRITE
}

// ---------------- partial l[j], 32x32 MFMA: plsum[b][iy][j] ----------------
// A = theta (rows = i, staged in LDS), B = phi (cols = j, in regs).
// D[row=i][col=j]; lane sums exp over its 16 i-rows for j = j0 + w*32 + (lane&31).
__global__ __launch_bounds__(256, 4) void k_lsum(
    const short* __restrict__ phiB, const short* __restrict__ thetaB,
    float* __restrict__ plsum) {
  __shared__ short thT[2][32 * 128];   // 8KB each, chunk-swizzled ^(row&7)
  const int tid = threadIdx.x, lane = tid & 63, w = tid >> 6;
  const int il = lane & 31, h = lane >> 5;
  const int j0 = blockIdx.x * 128, iy = blockIdx.y, b = blockIdx.z;
  const short* phb = phiB + (size_t)b * NPOS * NCI;
  const short* thb = thetaB + (size_t)b * NPOS * NCI + (size_t)iy * (NPOS / ISPLIT) * NCI;
  bf16x8 pf[8];
  {
    const short* pr = phb + (size_t)(j0 + w * 32 + il) * NCI;
#pragma unroll
    for (int kk = 0; kk < 8; ++kk) pf[kk] = *(const bf16x8*)(pr + kk * 16 + h * 8);
  }
  float lsum = 0.f;
  int4 rt[2];
  const int NIT = NPOS / ISPLIT / 32;   // 16
#define LSUM_LOAD(it)                                                         \
  { _Pragma("unroll") for (int r = 0; r < 2; ++r) {                           \
      int s = tid + r * 256; int row = s >> 4, c = s & 15;                    \
      rt[r] = *(const int4*)(thb + (size_t)((it) * 32 + row) * NCI + c * 8); } }
#define LSUM_WRITE(buf)                                                       \
  { _Pragma("unroll") for (int r = 0; r < 2; ++r) {                           \
      int s = tid + r * 256; int row = s >> 4, c = s & 15;                    \
      *(int4*)(&thT[buf][row * 128 + ((c ^ (row & 7)) * 8)]) = rt[r]; } }
  LSUM_LOAD(0); LSUM_WRITE(0); __syncthreads();
  int cur = 0;
  const int swz = il & 7;
  for (int it = 0; it < NIT; ++it) {
    if (it + 1 < NIT) LSUM_LOAD(it + 1);
    f32x16 s16;
#pragma unroll
    for (int r = 0; r < 16; ++r) s16[r] = 0.f;
#pragma unroll
    for (int kk = 0; kk < 8; ++kk) {
      bf16x8 a = *(const bf16x8*)(&thT[cur][il * 128 + (((2 * kk + h) ^ swz) * 8)]);
      s16 = __builtin_amdgcn_mfma_f32_32x32x16_bf16(a, pf[kk], s16, 0, 0, 0);
    }
#pragma unroll
    for (int r = 0; r < 16; ++r) lsum += __expf(s16[r]);
    if (it + 1 < NIT) LSUM_WRITE(cur ^ 1);
    __syncthreads();
    cur ^= 1;
  }
  lsum += __shfl_xor(lsum, 32);
  if (h == 0)
    plsum[((size_t)(b * ISPLIT + iy) << 12) + j0 + w * 32 + il] = lsum;
#undef LSUM_LOAD
#undef LSUM_WRITE
}

// ---------------- combine partials -> linv ----------------
__global__ void k_lcomb(const float* __restrict__ plsum, float* __restrict__ linv) {
  int i = blockIdx.x * 256 + threadIdx.x;   // NB*NPOS
  int b = i >> 12, j = i & (NPOS - 1);
  float s = 0.f;
#pragma unroll
  for (int t = 0; t < ISPLIT; ++t) s += plsum[((size_t)(b * ISPLIT + t) << 12) + j];
  linv[i] = 1.0f / s;
}

// ---------------- fold linv into g: gB[cc][p] *= linv[p] ----------------
__global__ void k_scale_g(short* __restrict__ gB, const float* __restrict__ linv) {
  size_t e = ((size_t)blockIdx.x * 256 + threadIdx.x) * 8;
  int b = (int)(e >> 20);
  int p = (int)(e & (NPOS - 1));
  __align__(16) short v[8];
  *(int4*)v = *(const int4*)(gB + e);
  const float* lv = linv + ((size_t)b << 12) + p;
#pragma unroll
  for (int k = 0; k < 8; ++k) v[k] = (short)f2bf(bf2f(v[k]) * lv[k]);
  *(int4*)(gB + e) = *(const int4*)v;
}

// ---------------- attention, 32x32x16 MFMA (R14-verified, manual f2bf packs) ----
// Block: 128 i rows (wave w owns i = i0+w*32+(lane&31)); j-quarter, tiles of 32 j.
// S^T = mfma32(A=phi, B=theta-in-regs) -> per-wave pT; PV = mfma32(A=pT, B=gT).
// omidP[jq][b][cc][i] bf16.
__global__ __launch_bounds__(256, 2) void k_attn(
    const short* __restrict__ phiB, const short* __restrict__ thetaB,
    const short* __restrict__ gB, short* __restrict__ omidP) {
  __shared__ short phiT[2][32 * 128];   // 8KB each, chunk-swizzled ^(row&7)
  __shared__ short gT[2][256 * 32];     // 16KB each, slot-swizzled ^((row>>1)&3)
  __shared__ short pT[4][32 * 32];      // 2KB per wave, slot-swizzled
  const int tid = threadIdx.x, lane = tid & 63, w = tid >> 6;
  const int il = lane & 31, h = lane >> 5;
  const int key = (il >> 1) & 3;        // 16B-slot swizzle key (row = il)
  const int i0 = blockIdx.x * 128, jq = blockIdx.y, b = blockIdx.z;
  const short* phb = phiB + (size_t)b * NPOS * NCI;
  const short* thb = thetaB + (size_t)b * NPOS * NCI;
  const short* gb = gB + (size_t)b * NC * NPOS;
  short* om = omidP + ((size_t)(jq * NB + b)) * NC * NPOS;

  // theta B-frags: col i = i0 + w*32 + il, k-chunk kk*16 + h*8
  bf16x8 tf[8];
  {
    const short* tr = thb + (size_t)(i0 + w * 32 + il) * NCI;
#pragma unroll
    for (int kk = 0; kk < 8; ++kk) tf[kk] = *(const bf16x8*)(tr + kk * 16 + h * 8);
  }
  f32x16 acc[8];
#pragma unroll
  for (int i = 0; i < 8; ++i)
#pragma unroll
    for (int r = 0; r < 16; ++r) acc[i][r] = 0.f;

  int4 rphi[2], rg[4];
  const int NT = 32;                    // 32 j-tiles of 32 per quarter
  const int jbase = jq * 32;
#define ATTN_LOAD(jt)                                                          \
  { _Pragma("unroll") for (int r = 0; r < 2; ++r) {                            \
      int s = tid + r * 256; int row = s >> 4, c = s & 15;                     \
      rphi[r] = *(const int4*)(phb + (size_t)((jbase + (jt)) * 32 + row) * NCI + c * 8); } \
    _Pragma("unroll") for (int r = 0; r < 4; ++r) {                            \
      int s = tid + r * 256; int cc = s >> 2, c4 = s & 3;                      \
      rg[r] = *(const int4*)(gb + (size_t)cc * NPOS + (jbase + (jt)) * 32 + c4 * 8); } }
#define ATTN_WRITE(buf)                                                        \
  { _Pragma("unroll") for (int r = 0; r < 2; ++r) {                            \
      int s = tid + r * 256; int row = s >> 4, c = s & 15;                     \
      *(int4*)(&phiT[buf][row * 128 + ((c ^ (row & 7)) * 8)]) = rphi[r]; }     \
    _Pragma("unroll") for (int r = 0; r < 4; ++r) {                            \
      int s = tid + r * 256; int cc = s >> 2, c4 = s & 3;                      \
      *(int4*)(&gT[buf][cc * 32 + ((c4 ^ ((cc >> 1) & 3)) * 8)]) = rg[r]; } }
  ATTN_LOAD(0); ATTN_WRITE(0); __syncthreads();
  int cur = 0;
  for (int jt = 0; jt < NT; ++jt) {
    if (jt + 1 < NT) ATTN_LOAD(jt + 1);
    {
      const short* PH = &phiT[cur][0];
      short* PW = &pT[w][0];
      // ---- S^T: 32 j x 32 i, K=128 via 8 mfma 32x32x16 ----
      f32x16 s16;
#pragma unroll
      for (int r = 0; r < 16; ++r) s16[r] = 0.f;
      const int swp = il & 7;           // phi chunk swizzle (row = j = il)
#pragma unroll
      for (int kk = 0; kk < 8; ++kk) {
        bf16x8 a = *(const bf16x8*)(PH + il * 128 + (((2 * kk + h) ^ swp) * 8));
        s16 = __builtin_amdgcn_mfma_f32_32x32x16_bf16(a, tf[kk], s16, 0, 0, 0);
      }
      // lane holds S^T[j=(r&3)+8*(r>>2)+4h][i = i0+w*32+il]; P = exp(S)
      // write P[i=il][j] : slot g2 (j in [8g2,8g2+8)), 8B half h
#pragma unroll
      for (int g2 = 0; g2 < 4; ++g2) {
        unsigned short p0 = f2bf(__expf(s16[4 * g2 + 0]));
        unsigned short p1 = f2bf(__expf(s16[4 * g2 + 1]));
        unsigned short p2 = f2bf(__expf(s16[4 * g2 + 2]));
        unsigned short p3 = f2bf(__expf(s16[4 * g2 + 3]));
        unsigned int lo = (unsigned int)p0 | ((unsigned int)p1 << 16);
        unsigned int hi2 = (unsigned int)p2 | ((unsigned int)p3 << 16);
        *(uint2*)(PW + il * 32 + ((g2 ^ key) * 8) + 4 * h) = make_uint2(lo, hi2);
      }
      // ---- PV: wave's 32 i x all 256 cc ----
      const short* GT = &gT[cur][0];
      bf16x8 pa[2];
#pragma unroll
      for (int jh2 = 0; jh2 < 2; ++jh2)
        pa[jh2] = *(const bf16x8*)(PW + il * 32 + (((2 * jh2 + h) ^ key) * 8));
#pragma unroll
      for (int ct = 0; ct < 8; ++ct) {
#pragma unroll
        for (int jh2 = 0; jh2 < 2; ++jh2) {
          bf16x8 bg = *(const bf16x8*)(GT + (ct * 32 + il) * 32 + (((2 * jh2 + h) ^ key) * 8));
          acc[ct] = __builtin_amdgcn_mfma_f32_32x32x16_bf16(pa[jh2], bg, acc[ct], 0, 0, 0);
        }
      }
    }
    if (jt + 1 < NT) ATTN_WRITE(cur ^ 1);
    __syncthreads();
    cur ^= 1;
  }
  // store bf16: acc[ct]: cc = ct*32+il, i = i0+w*32 + (r&3)+8*(r>>2)+4h
#pragma unroll
  for (int ct = 0; ct < 8; ++ct)
#pragma unroll
    for (int g2 = 0; g2 < 4; ++g2) {
      __align__(8) short pv[4];
#pragma unroll
      for (int e = 0; e < 4; ++e) pv[e] = (short)f2bf(acc[ct][4 * g2 + e]);
      size_t o = (size_t)(ct * 32 + il) * NPOS + i0 + w * 32 + 8 * g2 + 4 * h;
      *(uint2*)(om + o) = *(const uint2*)pv;
    }
#undef ATTN_LOAD
#undef ATTN_WRITE
}

extern "C" void kernel_launch(void* const* d_in, const int* in_sizes, int n_in,
                              void* d_out, int out_size, void* d_ws, size_t ws_size,
                              hipStream_t stream) {
  (void)in_sizes; (void)n_in; (void)out_size; (void)ws_size;
  const float* x0      = (const float*)d_in[0];
  const float* x       = (const float*)d_in[1];
  const float* x_dsm   = (const float*)d_in[2];
  const float* w_phi   = (const float*)d_in[3];
  const float* w_theta = (const float*)d_in[4];
  const float* w_g     = (const float*)d_in[5];
  const float* w_mask  = (const float*)d_in[6];
  float* outp = (float*)d_out;

  short* sp = (short*)d_ws;
  short* wb_phi   = sp; sp += 32768;
  short* wb_theta = sp; sp += 32768;
  short* wb_g     = sp; sp += 131072;
  short* wb_mask  = sp; sp += 131072;
  short* xT   = sp; sp += (size_t)NB * NPOS * NC;          // 8MB
  short* xdT  = sp; sp += (size_t)NB * NPOS * NC;          // 8MB
  short* x0T  = sp; sp += (size_t)NB * NPOS * NC2;         // 16MB
  short* phiB   = sp; sp += (size_t)NB * NPOS * NCI;       // 4MB
  short* thetaB = sp; sp += (size_t)NB * NPOS * NCI;       // 4MB
  short* gBuf   = sp; sp += (size_t)NB * NC * NPOS;        // 8MB
  float* linv = (float*)sp; sp += 2 * (size_t)NB * NPOS;
  float* plsum = (float*)sp;                               // [b][ISPLIT][NPOS]
  short* omidP = xT;       // 4 bf16 partials x 8MB = 32MB, aliases dead xT/xdT/x0T
  short* omidT = phiB;     // 8MB bf16 [b][p][cc], aliases dead phiB/thetaB

  k_cast4<<<dim3(1280), 256, 0, stream>>>(w_phi, wb_phi, 32768,
                                          w_theta, wb_theta, 32768,
                                          w_g, wb_g, 131072,
                                          w_mask, wb_mask, 131072);

  k_tcast_all<<<dim3(64, 16, NB), 256, 0, stream>>>(x, x_dsm, x0, xT, xdT, x0T);

  k_gemm<true, false><<<dim3(64, 2, NB), 256, 0, stream>>>(
      wb_phi, xT, phiB, nullptr, NC, NCI, 0, (size_t)NPOS * NC, (size_t)NPOS * NCI);
  k_gemm<true, false><<<dim3(64, 2, NB), 256, 0, stream>>>(
      wb_theta, xdT, thetaB, nullptr, NC, NCI, 0, (size_t)NPOS * NC, (size_t)NPOS * NCI);
  k_gemm<true, false><<<dim3(4, 64, NB), 256, 0, stream>>>(
      x0T, wb_g, gBuf, nullptr, NC2, NPOS, (size_t)NPOS * NC2, 0, (size_t)NC * NPOS);

  k_lsum<<<dim3(NPOS / 128, ISPLIT, NB), 256, 0, stream>>>(phiB, thetaB, plsum);
  k_lcomb<<<dim3(NB * NPOS / 256), 256, 0, stream>>>(plsum, linv);
  k_scale_g<<<dim3(2048), 256, 0, stream>>>(gBuf, linv);

  k_attn<<<dim3(NPOS / 128, 4, NB), 256, 0, stream>>>(phiB, thetaB, gBuf, omidP);

  k_tcast4<<<dim3(64, 4, NB), 256, 0, stream>>>(omidP, omidT);

  k_gemm<false, true><<<dim3(8, 64, NB), 256, 0, stream>>>(
      omidT, wb_mask, outp, x0, NC, NPOS, (size_t)NPOS * NC, 0, (size_t)NC2 * NPOS);
}

// Round 20
// 231.620 us; speedup vs baseline: 1.9601x; 1.0005x over previous
//
#include <hip/hip_runtime.h>
#include <math.h>

#define NB 4
#define NC 256
#define NCI 128
#define NC2 512
#define NPOS 4096
#define ISPLIT 8

using bf16x8 = __attribute__((ext_vector_type(8))) short;
using f32x4  = __attribute__((ext_vector_type(4))) float;
using f32x16 = __attribute__((ext_vector_type(16))) float;

__device__ inline unsigned short f2bf(float f) {
  unsigned int u = __float_as_uint(f);
  u = (u + 0x7fffu + ((u >> 16) & 1u)) >> 16;
  return (unsigned short)u;
}
__device__ inline float bf2f(short s) {
  return __uint_as_float(((unsigned int)(unsigned short)s) << 16);
}

// ---------------- cast 4 weight tensors fp32 -> bf16 ----------------
__global__ void k_cast4(const float* __restrict__ s0, short* __restrict__ d0, int n0,
                        const float* __restrict__ s1, short* __restrict__ d1, int n1,
                        const float* __restrict__ s2, short* __restrict__ d2, int n2,
                        const float* __restrict__ s3, short* __restrict__ d3, int n3) {
  int i = blockIdx.x * 256 + threadIdx.x;
  if (i < n0) { d0[i] = (short)f2bf(s0[i]); return; } i -= n0;
  if (i < n1) { d1[i] = (short)f2bf(s1[i]); return; } i -= n1;
  if (i < n2) { d2[i] = (short)f2bf(s2[i]); return; } i -= n2;
  if (i < n3) { d3[i] = (short)f2bf(s3[i]); }
}

// ---------------- fused transpose-cast for x, x_dsm, x0 ----------------
__global__ __launch_bounds__(256) void k_tcast_all(
    const float* __restrict__ x, const float* __restrict__ xdsm,
    const float* __restrict__ x0, short* __restrict__ xT,
    short* __restrict__ xdT, short* __restrict__ x0T) {
  __shared__ float t[64][65];
  const int tid = threadIdx.x;
  const int y = blockIdx.y, c0 = blockIdx.x * 64, b = blockIdx.z;
  const float* in; short* out; int R, r0;
  if (y < 4)      { in = x;    out = xT;  R = NC;  r0 = y * 64; }
  else if (y < 8) { in = xdsm; out = xdT; R = NC;  r0 = (y - 4) * 64; }
  else            { in = x0;   out = x0T; R = NC2; r0 = (y - 8) * 64; }
  const size_t inBs = (size_t)R * NPOS, outBs = (size_t)NPOS * R;
  {
    int r = tid >> 2, cc = (tid & 3) * 16;
    const float* ib = in + (size_t)b * inBs + (size_t)(r0 + r) * NPOS + c0 + cc;
#pragma unroll
    for (int i = 0; i < 4; ++i) {
      float4 v = *(const float4*)(ib + i * 4);
      t[r][cc + i * 4 + 0] = v.x; t[r][cc + i * 4 + 1] = v.y;
      t[r][cc + i * 4 + 2] = v.z; t[r][cc + i * 4 + 3] = v.w;
    }
  }
  __syncthreads();
  {
    int c = tid >> 2, rr = (tid & 3) * 16;
    __align__(16) short v[16];
#pragma unroll
    for (int i = 0; i < 16; ++i) v[i] = (short)f2bf(t[rr + i][c]);
    short* ob = out + (size_t)b * outBs + (size_t)(c0 + c) * R + r0 + rr;
    *(int4*)(ob) = *(const int4*)(v);
    *(int4*)(ob + 8) = *(const int4*)(v + 8);
  }
}

// ---------------- sum 4 bf16 partials [p][b][cc][i] -> transpose [b][i][cc] bf16
__global__ __launch_bounds__(256) void k_tcast4(
    const short* __restrict__ inP, short* __restrict__ out) {
  __shared__ float t[64][65];
  const int tid = threadIdx.x;
  const int r0 = blockIdx.y * 64, c0 = blockIdx.x * 64, b = blockIdx.z;
  {
    int r = tid >> 2, cc = (tid & 3) * 16;
    float tacc[16] = {};
#pragma unroll
    for (int p = 0; p < 4; ++p) {
      const short* ib = inP + ((size_t)p * NB + b) * NC * NPOS +
                        (size_t)(r0 + r) * NPOS + c0 + cc;
      bf16x8 a = *(const bf16x8*)(ib);
      bf16x8 a2 = *(const bf16x8*)(ib + 8);
#pragma unroll
      for (int i = 0; i < 8; ++i) { tacc[i] += bf2f(a[i]); tacc[8 + i] += bf2f(a2[i]); }
    }
#pragma unroll
    for (int i = 0; i < 16; ++i) t[r][cc + i] = tacc[i];
  }
  __syncthreads();
  {
    int c = tid >> 2, rr = (tid & 3) * 16;
    __align__(16) short v[16];
#pragma unroll
    for (int i = 0; i < 16; ++i) v[i] = (short)f2bf(t[rr + i][c]);
    short* ob = out + (size_t)b * (size_t)NPOS * NC + (size_t)(c0 + c) * NC + r0 + rr;
    *(int4*)(ob) = *(const int4*)(v);
    *(int4*)(ob + 8) = *(const int4*)(v + 8);
  }
}

// ---------------- generic bf16 MFMA GEMM ----------------
template<bool OUT_BF16, bool HAS_RES>
__global__ __launch_bounds__(256, 2) void k_gemm(
    const short* __restrict__ A, const short* __restrict__ B,
    void* __restrict__ outv, const float* __restrict__ res,
    int K, int sN, size_t aBs, size_t bBs, size_t oBs) {
  __shared__ short As[2][64 * 64];
  __shared__ short Bs_[2][64 * 64];
  const int tid = threadIdx.x, lane = tid & 63, w = tid >> 6;
  const int x = lane & 15, q = lane >> 4;
  const int wm = (w & 1) * 32, wn = (w >> 1) * 32;
  const int n0 = blockIdx.x * 64, m0 = blockIdx.y * 64, b = blockIdx.z;
  const short* Ab = A + (size_t)b * aBs + (size_t)m0 * K;
  const short* Bb = B + (size_t)b * bBs + (size_t)n0 * K;
  const int r = tid >> 2, cth = tid & 3;
  f32x4 acc[2][2];
  acc[0][0] = acc[0][1] = acc[1][0] = acc[1][1] = (f32x4){0.f, 0.f, 0.f, 0.f};
  int4 ra[2], rb[2];
  const int NK = K >> 6;
#define GLOAD(kt)                                                              \
  { _Pragma("unroll") for (int i = 0; i < 2; ++i) {                            \
      ra[i] = *(const int4*)(Ab + (size_t)r * K + (kt) * 64 + (cth + i * 4) * 8); \
      rb[i] = *(const int4*)(Bb + (size_t)r * K + (kt) * 64 + (cth + i * 4) * 8); } }
#define GWRITE(buf)                                                            \
  { _Pragma("unroll") for (int i = 0; i < 2; ++i) {                            \
      *(int4*)(&As[buf][r * 64 + (((cth + i * 4) ^ (r & 7)) * 8)]) = ra[i];    \
      *(int4*)(&Bs_[buf][r * 64 + (((cth + i * 4) ^ (r & 7)) * 8)]) = rb[i]; } }
  GLOAD(0); GWRITE(0); __syncthreads();
  int cur = 0;
  for (int kt = 0; kt < NK; ++kt) {
    if (kt + 1 < NK) GLOAD(kt + 1);
    bf16x8 af[2][2], bfr[2][2];
#pragma unroll
    for (int ms = 0; ms < 2; ++ms) {
      int rowm = wm + ms * 16 + x;
#pragma unroll
      for (int ks = 0; ks < 2; ++ks)
        af[ms][ks] = *(const bf16x8*)(&As[cur][rowm * 64 + (((ks * 4 + q) ^ (rowm & 7)) * 8)]);
    }
#pragma unroll
    for (int ns = 0; ns < 2; ++ns) {
      int rown = wn + ns * 16 + x;
#pragma unroll
      for (int ks = 0; ks < 2; ++ks)
        bfr[ns][ks] = *(const bf16x8*)(&Bs_[cur][rown * 64 + (((ks * 4 + q) ^ (rown & 7)) * 8)]);
    }
#pragma unroll
    for (int ms = 0; ms < 2; ++ms)
#pragma unroll
      for (int ns = 0; ns < 2; ++ns)
#pragma unroll
        for (int ks = 0; ks < 2; ++ks)
          acc[ms][ns] = __builtin_amdgcn_mfma_f32_16x16x32_bf16(
              af[ms][ks], bfr[ns][ks], acc[ms][ns], 0, 0, 0);
    if (kt + 1 < NK) GWRITE(cur ^ 1);
    __syncthreads();
    cur ^= 1;
  }
#pragma unroll
  for (int ms = 0; ms < 2; ++ms)
#pragma unroll
    for (int ns = 0; ns < 2; ++ns) {
      int n = n0 + wn + ns * 16 + x;
      int m = m0 + wm + ms * 16 + q * 4;
      size_t off = (size_t)b * oBs + (size_t)n * sN + m;
      if (OUT_BF16) {
        __align__(8) short pv[4];
#pragma unroll
        for (int j = 0; j < 4; ++j) pv[j] = (short)f2bf(acc[ms][ns][j]);
        *(uint2*)((short*)outv + off) = *(const uint2*)pv;
      } else {
        float4 v = {acc[ms][ns][0], acc[ms][ns][1], acc[ms][ns][2], acc[ms][ns][3]};
        if (HAS_RES) {
          float4 rv = *(const float4*)(res + off);
          v.x += rv.x; v.y += rv.y; v.z += rv.z; v.w += rv.w;
        }
        *(float4*)((float*)outv + off) = v;
      }
    }
#undef GLOAD
#undef GWRITE
}

// ---------------- partial l[j], 32x32 MFMA: plsum[b][iy][j] ----------------
__global__ __launch_bounds__(256, 4) void k_lsum(
    const short* __restrict__ phiB, const short* __restrict__ thetaB,
    float* __restrict__ plsum) {
  __shared__ short thT[2][32 * 128];   // 8KB each, chunk-swizzled ^(row&7)
  const int tid = threadIdx.x, lane = tid & 63, w = tid >> 6;
  const int il = lane & 31, h = lane >> 5;
  const int j0 = blockIdx.x * 128, iy = blockIdx.y, b = blockIdx.z;
  const short* phb = phiB + (size_t)b * NPOS * NCI;
  const short* thb = thetaB + (size_t)b * NPOS * NCI + (size_t)iy * (NPOS / ISPLIT) * NCI;
  bf16x8 pf[8];
  {
    const short* pr = phb + (size_t)(j0 + w * 32 + il) * NCI;
#pragma unroll
    for (int kk = 0; kk < 8; ++kk) pf[kk] = *(const bf16x8*)(pr + kk * 16 + h * 8);
  }
  float lsum = 0.f;
  int4 rt[2];
  const int NIT = NPOS / ISPLIT / 32;   // 16
#define LSUM_LOAD(it)                                                         \
  { _Pragma("unroll") for (int r = 0; r < 2; ++r) {                           \
      int s = tid + r * 256; int row = s >> 4, c = s & 15;                    \
      rt[r] = *(const int4*)(thb + (size_t)((it) * 32 + row) * NCI + c * 8); } }
#define LSUM_WRITE(buf)                                                       \
  { _Pragma("unroll") for (int r = 0; r < 2; ++r) {                           \
      int s = tid + r * 256; int row = s >> 4, c = s & 15;                    \
      *(int4*)(&thT[buf][row * 128 + ((c ^ (row & 7)) * 8)]) = rt[r]; } }
  LSUM_LOAD(0); LSUM_WRITE(0); __syncthreads();
  int cur = 0;
  const int swz = il & 7;
  for (int it = 0; it < NIT; ++it) {
    if (it + 1 < NIT) LSUM_LOAD(it + 1);
    f32x16 s16;
#pragma unroll
    for (int r = 0; r < 16; ++r) s16[r] = 0.f;
#pragma unroll
    for (int kk = 0; kk < 8; ++kk) {
      bf16x8 a = *(const bf16x8*)(&thT[cur][il * 128 + (((2 * kk + h) ^ swz) * 8)]);
      s16 = __builtin_amdgcn_mfma_f32_32x32x16_bf16(a, pf[kk], s16, 0, 0, 0);
    }
#pragma unroll
    for (int r = 0; r < 16; ++r) lsum += __expf(s16[r]);
    if (it + 1 < NIT) LSUM_WRITE(cur ^ 1);
    __syncthreads();
    cur ^= 1;
  }
  lsum += __shfl_xor(lsum, 32);
  if (h == 0)
    plsum[((size_t)(b * ISPLIT + iy) << 12) + j0 + w * 32 + il] = lsum;
#undef LSUM_LOAD
#undef LSUM_WRITE
}

// ---------------- combine partials -> linv ----------------
__global__ void k_lcomb(const float* __restrict__ plsum, float* __restrict__ linv) {
  int i = blockIdx.x * 256 + threadIdx.x;   // NB*NPOS
  int b = i >> 12, j = i & (NPOS - 1);
  float s = 0.f;
#pragma unroll
  for (int t = 0; t < ISPLIT; ++t) s += plsum[((size_t)(b * ISPLIT + t) << 12) + j];
  linv[i] = 1.0f / s;
}

// ---------------- attention, 32x32x16 MFMA, linv folded into P ----------------
// Block: 128 i rows (wave w owns i = i0+w*32+(lane&31)); j-quarter, tiles of 32 j.
// S^T = mfma32(A=phi, B=theta-in-regs); P = exp(S)*linv[j] -> per-wave pT;
// PV = mfma32(A=pT, B=gT). omidP[jq][b][cc][i] bf16.
__global__ __launch_bounds__(256, 2) void k_attn(
    const short* __restrict__ phiB, const short* __restrict__ thetaB,
    const short* __restrict__ gB, const float* __restrict__ linv,
    short* __restrict__ omidP) {
  __shared__ short phiT[2][32 * 128];   // 8KB each, chunk-swizzled ^(row&7)
  __shared__ short gT[2][256 * 32];     // 16KB each, slot-swizzled ^((row>>1)&3)
  __shared__ short pT[4][32 * 32];      // 2KB per wave, slot-swizzled
  const int tid = threadIdx.x, lane = tid & 63, w = tid >> 6;
  const int il = lane & 31, h = lane >> 5;
  const int key = (il >> 1) & 3;        // 16B-slot swizzle key (row = il)
  const int i0 = blockIdx.x * 128, jq = blockIdx.y, b = blockIdx.z;
  const short* phb = phiB + (size_t)b * NPOS * NCI;
  const short* thb = thetaB + (size_t)b * NPOS * NCI;
  const short* gb = gB + (size_t)b * NC * NPOS;
  const float* lvb = linv + ((size_t)b << 12);
  short* om = omidP + ((size_t)(jq * NB + b)) * NC * NPOS;

  // theta B-frags: col i = i0 + w*32 + il, k-chunk kk*16 + h*8
  bf16x8 tf[8];
  {
    const short* tr = thb + (size_t)(i0 + w * 32 + il) * NCI;
#pragma unroll
    for (int kk = 0; kk < 8; ++kk) tf[kk] = *(const bf16x8*)(tr + kk * 16 + h * 8);
  }
  f32x16 acc[8];
#pragma unroll
  for (int i = 0; i < 8; ++i)
#pragma unroll
    for (int r = 0; r < 16; ++r) acc[i][r] = 0.f;

  int4 rphi[2], rg[4];
  const int NT = 32;                    // 32 j-tiles of 32 per quarter
  const int jbase = jq * 32;
#define ATTN_LOAD(jt)                                                          \
  { _Pragma("unroll") for (int r = 0; r < 2; ++r) {                            \
      int s = tid + r * 256; int row = s >> 4, c = s & 15;                     \
      rphi[r] = *(const int4*)(phb + (size_t)((jbase + (jt)) * 32 + row) * NCI + c * 8); } \
    _Pragma("unroll") for (int r = 0; r < 4; ++r) {                            \
      int s = tid + r * 256; int cc = s >> 2, c4 = s & 3;                      \
      rg[r] = *(const int4*)(gb + (size_t)cc * NPOS + (jbase + (jt)) * 32 + c4 * 8); } }
#define ATTN_WRITE(buf)                                                        \
  { _Pragma("unroll") for (int r = 0; r < 2; ++r) {                            \
      int s = tid + r * 256; int row = s >> 4, c = s & 15;                     \
      *(int4*)(&phiT[buf][row * 128 + ((c ^ (row & 7)) * 8)]) = rphi[r]; }     \
    _Pragma("unroll") for (int r = 0; r < 4; ++r) {                            \
      int s = tid + r * 256; int cc = s >> 2, c4 = s & 3;                      \
      *(int4*)(&gT[buf][cc * 32 + ((c4 ^ ((cc >> 1) & 3)) * 8)]) = rg[r]; } }
  ATTN_LOAD(0); ATTN_WRITE(0); __syncthreads();
  int cur = 0;
  for (int jt = 0; jt < NT; ++jt) {
    if (jt + 1 < NT) ATTN_LOAD(jt + 1);
    {
      const short* PH = &phiT[cur][0];
      short* PW = &pT[w][0];
      // ---- S^T: 32 j x 32 i, K=128 via 8 mfma 32x32x16 ----
      f32x16 s16;
#pragma unroll
      for (int r = 0; r < 16; ++r) s16[r] = 0.f;
      const int swp = il & 7;           // phi chunk swizzle (row = j = il)
#pragma unroll
      for (int kk = 0; kk < 8; ++kk) {
        bf16x8 a = *(const bf16x8*)(PH + il * 128 + (((2 * kk + h) ^ swp) * 8));
        s16 = __builtin_amdgcn_mfma_f32_32x32x16_bf16(a, tf[kk], s16, 0, 0, 0);
      }
      // lane holds S^T[j=(r&3)+8*(r>>2)+4h][i = i0+w*32+il]; P = exp(S)*linv[j]
      // j_local for g2: 8*g2 + 4*h + (r&3)  -> contiguous float4 of linv
#pragma unroll
      for (int g2 = 0; g2 < 4; ++g2) {
        float4 lv = *(const float4*)(lvb + (jbase + jt) * 32 + 8 * g2 + 4 * h);
        unsigned short p0 = f2bf(__expf(s16[4 * g2 + 0]) * lv.x);
        unsigned short p1 = f2bf(__expf(s16[4 * g2 + 1]) * lv.y);
        unsigned short p2 = f2bf(__expf(s16[4 * g2 + 2]) * lv.z);
        unsigned short p3 = f2bf(__expf(s16[4 * g2 + 3]) * lv.w);
        unsigned int lo = (unsigned int)p0 | ((unsigned int)p1 << 16);
        unsigned int hi2 = (unsigned int)p2 | ((unsigned int)p3 << 16);
        *(uint2*)(PW + il * 32 + ((g2 ^ key) * 8) + 4 * h) = make_uint2(lo, hi2);
      }
      // ---- PV: wave's 32 i x all 256 cc ----
      const short* GT = &gT[cur][0];
      bf16x8 pa[2];
#pragma unroll
      for (int jh2 = 0; jh2 < 2; ++jh2)
        pa[jh2] = *(const bf16x8*)(PW + il * 32 + (((2 * jh2 + h) ^ key) * 8));
#pragma unroll
      for (int ct = 0; ct < 8; ++ct) {
#pragma unroll
        for (int jh2 = 0; jh2 < 2; ++jh2) {
          bf16x8 bg = *(const bf16x8*)(GT + (ct * 32 + il) * 32 + (((2 * jh2 + h) ^ key) * 8));
          acc[ct] = __builtin_amdgcn_mfma_f32_32x32x16_bf16(pa[jh2], bg, acc[ct], 0, 0, 0);
        }
      }
    }
    if (jt + 1 < NT) ATTN_WRITE(cur ^ 1);
    __syncthreads();
    cur ^= 1;
  }
  // store bf16: acc[ct]: cc = ct*32+il, i = i0+w*32 + (r&3)+8*(r>>2)+4h
#pragma unroll
  for (int ct = 0; ct < 8; ++ct)
#pragma unroll
    for (int g2 = 0; g2 < 4; ++g2) {
      __align__(8) short pv[4];
#pragma unroll
      for (int e = 0; e < 4; ++e) pv[e] = (short)f2bf(acc[ct][4 * g2 + e]);
      size_t o = (size_t)(ct * 32 + il) * NPOS + i0 + w * 32 + 8 * g2 + 4 * h;
      *(uint2*)(om + o) = *(const uint2*)pv;
    }
#undef ATTN_LOAD
#undef ATTN_WRITE
}

extern "C" void kernel_launch(void* const* d_in, const int* in_sizes, int n_in,
                              void* d_out, int out_size, void* d_ws, size_t ws_size,
                              hipStream_t stream) {
  (void)in_sizes; (void)n_in; (void)out_size; (void)ws_size;
  const float* x0      = (const float*)d_in[0];
  const float* x       = (const float*)d_in[1];
  const float* x_dsm   = (const float*)d_in[2];
  const float* w_phi   = (const float*)d_in[3];
  const float* w_theta = (const float*)d_in[4];
  const float* w_g     = (const float*)d_in[5];
  const float* w_mask  = (const float*)d_in[6];
  float* outp = (float*)d_out;

  short* sp = (short*)d_ws;
  short* wb_phi   = sp; sp += 32768;
  short* wb_theta = sp; sp += 32768;
  short* wb_g     = sp; sp += 131072;
  short* wb_mask  = sp; sp += 131072;
  short* xT   = sp; sp += (size_t)NB * NPOS * NC;          // 8MB
  short* xdT  = sp; sp += (size_t)NB * NPOS * NC;          // 8MB
  short* x0T  = sp; sp += (size_t)NB * NPOS * NC2;         // 16MB
  short* phiB   = sp; sp += (size_t)NB * NPOS * NCI;       // 4MB
  short* thetaB = sp; sp += (size_t)NB * NPOS * NCI;       // 4MB
  short* gBuf   = sp; sp += (size_t)NB * NC * NPOS;        // 8MB
  float* linv = (float*)sp; sp += 2 * (size_t)NB * NPOS;
  float* plsum = (float*)sp;                               // [b][ISPLIT][NPOS]
  short* omidP = xT;       // 4 bf16 partials x 8MB = 32MB, aliases dead xT/xdT/x0T
  short* omidT = phiB;     // 8MB bf16 [b][p][cc], aliases dead phiB/thetaB

  k_cast4<<<dim3(1280), 256, 0, stream>>>(w_phi, wb_phi, 32768,
                                          w_theta, wb_theta, 32768,
                                          w_g, wb_g, 131072,
                                          w_mask, wb_mask, 131072);

  k_tcast_all<<<dim3(64, 16, NB), 256, 0, stream>>>(x, x_dsm, x0, xT, xdT, x0T);

  k_gemm<true, false><<<dim3(64, 2, NB), 256, 0, stream>>>(
      wb_phi, xT, phiB, nullptr, NC, NCI, 0, (size_t)NPOS * NC, (size_t)NPOS * NCI);
  k_gemm<true, false><<<dim3(64, 2, NB), 256, 0, stream>>>(
      wb_theta, xdT, thetaB, nullptr, NC, NCI, 0, (size_t)NPOS * NC, (size_t)NPOS * NCI);
  k_gemm<true, false><<<dim3(4, 64, NB), 256, 0, stream>>>(
      x0T, wb_g, gBuf, nullptr, NC2, NPOS, (size_t)NPOS * NC2, 0, (size_t)NC * NPOS);

  k_lsum<<<dim3(NPOS / 128, ISPLIT, NB), 256, 0, stream>>>(phiB, thetaB, plsum);
  k_lcomb<<<dim3(NB * NPOS / 256), 256, 0, stream>>>(plsum, linv);

  k_attn<<<dim3(NPOS / 128, 4, NB), 256, 0, stream>>>(phiB, thetaB, gBuf, linv, omidP);

  k_tcast4<<<dim3(64, 4, NB), 256, 0, stream>>>(omidP, omidT);

  k_gemm<false, true><<<dim3(8, 64, NB), 256, 0, stream>>>(
      omidT, wb_mask, outp, x0, NC, NPOS, (size_t)NPOS * NC, 0, (size_t)NC2 * NPOS);
}

// Round 21
// 229.570 us; speedup vs baseline: 1.9776x; 1.0089x over previous
//
#include <hip/hip_runtime.h>
#include <math.h>

#define NB 4
#define NC 256
#define NCI 128
#define NC2 512
#define NPOS 4096
#define ISPLIT 8

using bf16x8 = __attribute__((ext_vector_type(8))) short;
using f32x4  = __attribute__((ext_vector_type(4))) float;
using f32x16 = __attribute__((ext_vector_type(16))) float;

__device__ inline unsigned short f2bf(float f) {
  unsigned int u = __float_as_uint(f);
  u = (u + 0x7fffu + ((u >> 16) & 1u)) >> 16;
  return (unsigned short)u;
}
__device__ inline float bf2f(short s) {
  return __uint_as_float(((unsigned int)(unsigned short)s) << 16);
}

// ---------------- cast 4 weight tensors fp32 -> bf16 ----------------
__global__ void k_cast4(const float* __restrict__ s0, short* __restrict__ d0, int n0,
                        const float* __restrict__ s1, short* __restrict__ d1, int n1,
                        const float* __restrict__ s2, short* __restrict__ d2, int n2,
                        const float* __restrict__ s3, short* __restrict__ d3, int n3) {
  int i = blockIdx.x * 256 + threadIdx.x;
  if (i < n0) { d0[i] = (short)f2bf(s0[i]); return; } i -= n0;
  if (i < n1) { d1[i] = (short)f2bf(s1[i]); return; } i -= n1;
  if (i < n2) { d2[i] = (short)f2bf(s2[i]); return; } i -= n2;
  if (i < n3) { d3[i] = (short)f2bf(s3[i]); }
}

// ---------------- fused transpose-cast for x, x_dsm, x0 ----------------
__global__ __launch_bounds__(256) void k_tcast_all(
    const float* __restrict__ x, const float* __restrict__ xdsm,
    const float* __restrict__ x0, short* __restrict__ xT,
    short* __restrict__ xdT, short* __restrict__ x0T) {
  __shared__ float t[64][65];
  const int tid = threadIdx.x;
  const int y = blockIdx.y, c0 = blockIdx.x * 64, b = blockIdx.z;
  const float* in; short* out; int R, r0;
  if (y < 4)      { in = x;    out = xT;  R = NC;  r0 = y * 64; }
  else if (y < 8) { in = xdsm; out = xdT; R = NC;  r0 = (y - 4) * 64; }
  else            { in = x0;   out = x0T; R = NC2; r0 = (y - 8) * 64; }
  const size_t inBs = (size_t)R * NPOS, outBs = (size_t)NPOS * R;
  {
    int r = tid >> 2, cc = (tid & 3) * 16;
    const float* ib = in + (size_t)b * inBs + (size_t)(r0 + r) * NPOS + c0 + cc;
#pragma unroll
    for (int i = 0; i < 4; ++i) {
      float4 v = *(const float4*)(ib + i * 4);
      t[r][cc + i * 4 + 0] = v.x; t[r][cc + i * 4 + 1] = v.y;
      t[r][cc + i * 4 + 2] = v.z; t[r][cc + i * 4 + 3] = v.w;
    }
  }
  __syncthreads();
  {
    int c = tid >> 2, rr = (tid & 3) * 16;
    __align__(16) short v[16];
#pragma unroll
    for (int i = 0; i < 16; ++i) v[i] = (short)f2bf(t[rr + i][c]);
    short* ob = out + (size_t)b * outBs + (size_t)(c0 + c) * R + r0 + rr;
    *(int4*)(ob) = *(const int4*)(v);
    *(int4*)(ob + 8) = *(const int4*)(v + 8);
  }
}

// ---------------- sum 4 bf16 partials [p][b][cc][i] -> transpose [b][i][cc] bf16
__global__ __launch_bounds__(256) void k_tcast4(
    const short* __restrict__ inP, short* __restrict__ out) {
  __shared__ float t[64][65];
  const int tid = threadIdx.x;
  const int r0 = blockIdx.y * 64, c0 = blockIdx.x * 64, b = blockIdx.z;
  {
    int r = tid >> 2, cc = (tid & 3) * 16;
    float tacc[16] = {};
#pragma unroll
    for (int p = 0; p < 4; ++p) {
      const short* ib = inP + ((size_t)p * NB + b) * NC * NPOS +
                        (size_t)(r0 + r) * NPOS + c0 + cc;
      bf16x8 a = *(const bf16x8*)(ib);
      bf16x8 a2 = *(const bf16x8*)(ib + 8);
#pragma unroll
      for (int i = 0; i < 8; ++i) { tacc[i] += bf2f(a[i]); tacc[8 + i] += bf2f(a2[i]); }
    }
#pragma unroll
    for (int i = 0; i < 16; ++i) t[r][cc + i] = tacc[i];
  }
  __syncthreads();
  {
    int c = tid >> 2, rr = (tid & 3) * 16;
    __align__(16) short v[16];
#pragma unroll
    for (int i = 0; i < 16; ++i) v[i] = (short)f2bf(t[rr + i][c]);
    short* ob = out + (size_t)b * (size_t)NPOS * NC + (size_t)(c0 + c) * NC + r0 + rr;
    *(int4*)(ob) = *(const int4*)(v);
    *(int4*)(ob + 8) = *(const int4*)(v + 8);
  }
}

// ---------------- generic bf16 MFMA GEMM ----------------
// SCALE_M: multiply output by scaleM[b*NPOS + m] (per-m scale, m contiguous).
template<bool OUT_BF16, bool HAS_RES, bool SCALE_M>
__global__ __launch_bounds__(256, 2) void k_gemm(
    const short* __restrict__ A, const short* __restrict__ B,
    void* __restrict__ outv, const float* __restrict__ res,
    const float* __restrict__ scaleM,
    int K, int sN, size_t aBs, size_t bBs, size_t oBs) {
  __shared__ short As[2][64 * 64];
  __shared__ short Bs_[2][64 * 64];
  const int tid = threadIdx.x, lane = tid & 63, w = tid >> 6;
  const int x = lane & 15, q = lane >> 4;
  const int wm = (w & 1) * 32, wn = (w >> 1) * 32;
  const int n0 = blockIdx.x * 64, m0 = blockIdx.y * 64, b = blockIdx.z;
  const short* Ab = A + (size_t)b * aBs + (size_t)m0 * K;
  const short* Bb = B + (size_t)b * bBs + (size_t)n0 * K;
  const int r = tid >> 2, cth = tid & 3;
  f32x4 acc[2][2];
  acc[0][0] = acc[0][1] = acc[1][0] = acc[1][1] = (f32x4){0.f, 0.f, 0.f, 0.f};
  int4 ra[2], rb[2];
  const int NK = K >> 6;
#define GLOAD(kt)                                                              \
  { _Pragma("unroll") for (int i = 0; i < 2; ++i) {                            \
      ra[i] = *(const int4*)(Ab + (size_t)r * K + (kt) * 64 + (cth + i * 4) * 8); \
      rb[i] = *(const int4*)(Bb + (size_t)r * K + (kt) * 64 + (cth + i * 4) * 8); } }
#define GWRITE(buf)                                                            \
  { _Pragma("unroll") for (int i = 0; i < 2; ++i) {                            \
      *(int4*)(&As[buf][r * 64 + (((cth + i * 4) ^ (r & 7)) * 8)]) = ra[i];    \
      *(int4*)(&Bs_[buf][r * 64 + (((cth + i * 4) ^ (r & 7)) * 8)]) = rb[i]; } }
  GLOAD(0); GWRITE(0); __syncthreads();
  int cur = 0;
  for (int kt = 0; kt < NK; ++kt) {
    if (kt + 1 < NK) GLOAD(kt + 1);
    bf16x8 af[2][2], bfr[2][2];
#pragma unroll
    for (int ms = 0; ms < 2; ++ms) {
      int rowm = wm + ms * 16 + x;
#pragma unroll
      for (int ks = 0; ks < 2; ++ks)
        af[ms][ks] = *(const bf16x8*)(&As[cur][rowm * 64 + (((ks * 4 + q) ^ (rowm & 7)) * 8)]);
    }
#pragma unroll
    for (int ns = 0; ns < 2; ++ns) {
      int rown = wn + ns * 16 + x;
#pragma unroll
      for (int ks = 0; ks < 2; ++ks)
        bfr[ns][ks] = *(const bf16x8*)(&Bs_[cur][rown * 64 + (((ks * 4 + q) ^ (rown & 7)) * 8)]);
    }
#pragma unroll
    for (int ms = 0; ms < 2; ++ms)
#pragma unroll
      for (int ns = 0; ns < 2; ++ns)
#pragma unroll
        for (int ks = 0; ks < 2; ++ks)
          acc[ms][ns] = __builtin_amdgcn_mfma_f32_16x16x32_bf16(
              af[ms][ks], bfr[ns][ks], acc[ms][ns], 0, 0, 0);
    if (kt + 1 < NK) GWRITE(cur ^ 1);
    __syncthreads();
    cur ^= 1;
  }
#pragma unroll
  for (int ms = 0; ms < 2; ++ms)
#pragma unroll
    for (int ns = 0; ns < 2; ++ns) {
      int n = n0 + wn + ns * 16 + x;
      int m = m0 + wm + ms * 16 + q * 4;
      size_t off = (size_t)b * oBs + (size_t)n * sN + m;
      float4 sv = {1.f, 1.f, 1.f, 1.f};
      if (SCALE_M) sv = *(const float4*)(scaleM + ((size_t)b << 12) + m);
      if (OUT_BF16) {
        __align__(8) short pv[4];
        pv[0] = (short)f2bf(acc[ms][ns][0] * sv.x);
        pv[1] = (short)f2bf(acc[ms][ns][1] * sv.y);
        pv[2] = (short)f2bf(acc[ms][ns][2] * sv.z);
        pv[3] = (short)f2bf(acc[ms][ns][3] * sv.w);
        *(uint2*)((short*)outv + off) = *(const uint2*)pv;
      } else {
        float4 v = {acc[ms][ns][0], acc[ms][ns][1], acc[ms][ns][2], acc[ms][ns][3]};
        if (HAS_RES) {
          float4 rv = *(const float4*)(res + off);
          v.x += rv.x; v.y += rv.y; v.z += rv.z; v.w += rv.w;
        }
        *(float4*)((float*)outv + off) = v;
      }
    }
#undef GLOAD
#undef GWRITE
}

// ---------------- partial l[j], 32x32 MFMA: plsum[b][iy][j] ----------------
__global__ __launch_bounds__(256, 4) void k_lsum(
    const short* __restrict__ phiB, const short* __restrict__ thetaB,
    float* __restrict__ plsum) {
  __shared__ short thT[2][32 * 128];   // 8KB each, chunk-swizzled ^(row&7)
  const int tid = threadIdx.x, lane = tid & 63, w = tid >> 6;
  const int il = lane & 31, h = lane >> 5;
  const int j0 = blockIdx.x * 128, iy = blockIdx.y, b = blockIdx.z;
  const short* phb = phiB + (size_t)b * NPOS * NCI;
  const short* thb = thetaB + (size_t)b * NPOS * NCI + (size_t)iy * (NPOS / ISPLIT) * NCI;
  bf16x8 pf[8];
  {
    const short* pr = phb + (size_t)(j0 + w * 32 + il) * NCI;
#pragma unroll
    for (int kk = 0; kk < 8; ++kk) pf[kk] = *(const bf16x8*)(pr + kk * 16 + h * 8);
  }
  float lsum = 0.f;
  int4 rt[2];
  const int NIT = NPOS / ISPLIT / 32;   // 16
#define LSUM_LOAD(it)                                                         \
  { _Pragma("unroll") for (int r = 0; r < 2; ++r) {                           \
      int s = tid + r * 256; int row = s >> 4, c = s & 15;                    \
      rt[r] = *(const int4*)(thb + (size_t)((it) * 32 + row) * NCI + c * 8); } }
#define LSUM_WRITE(buf)                                                       \
  { _Pragma("unroll") for (int r = 0; r < 2; ++r) {                           \
      int s = tid + r * 256; int row = s >> 4, c = s & 15;                    \
      *(int4*)(&thT[buf][row * 128 + ((c ^ (row & 7)) * 8)]) = rt[r]; } }
  LSUM_LOAD(0); LSUM_WRITE(0); __syncthreads();
  int cur = 0;
  const int swz = il & 7;
  for (int it = 0; it < NIT; ++it) {
    if (it + 1 < NIT) LSUM_LOAD(it + 1);
    f32x16 s16;
#pragma unroll
    for (int r = 0; r < 16; ++r) s16[r] = 0.f;
#pragma unroll
    for (int kk = 0; kk < 8; ++kk) {
      bf16x8 a = *(const bf16x8*)(&thT[cur][il * 128 + (((2 * kk + h) ^ swz) * 8)]);
      s16 = __builtin_amdgcn_mfma_f32_32x32x16_bf16(a, pf[kk], s16, 0, 0, 0);
    }
#pragma unroll
    for (int r = 0; r < 16; ++r) lsum += __expf(s16[r]);
    if (it + 1 < NIT) LSUM_WRITE(cur ^ 1);
    __syncthreads();
    cur ^= 1;
  }
  lsum += __shfl_xor(lsum, 32);
  if (h == 0)
    plsum[((size_t)(b * ISPLIT + iy) << 12) + j0 + w * 32 + il] = lsum;
#undef LSUM_LOAD
#undef LSUM_WRITE
}

// ---------------- combine partials -> linv ----------------
__global__ void k_lcomb(const float* __restrict__ plsum, float* __restrict__ linv) {
  int i = blockIdx.x * 256 + threadIdx.x;   // NB*NPOS
  int b = i >> 12, j = i & (NPOS - 1);
  float s = 0.f;
#pragma unroll
  for (int t = 0; t < ISPLIT; ++t) s += plsum[((size_t)(b * ISPLIT + t) << 12) + j];
  linv[i] = 1.0f / s;
}

// ---------------- attention, 32x32x16 MFMA (R19-verified) ----------------
// Block: 128 i rows (wave w owns i = i0+w*32+(lane&31)); j-quarter, tiles of 32 j.
// S^T = mfma32(A=phi, B=theta-in-regs) -> per-wave pT; PV = mfma32(A=pT, B=gT).
// omidP[jq][b][cc][i] bf16.  g is pre-scaled by linv (g-GEMM epilogue).
__global__ __launch_bounds__(256, 2) void k_attn(
    const short* __restrict__ phiB, const short* __restrict__ thetaB,
    const short* __restrict__ gB, short* __restrict__ omidP) {
  __shared__ short phiT[2][32 * 128];   // 8KB each, chunk-swizzled ^(row&7)
  __shared__ short gT[2][256 * 32];     // 16KB each, slot-swizzled ^((row>>1)&3)
  __shared__ short pT[4][32 * 32];      // 2KB per wave, slot-swizzled
  const int tid = threadIdx.x, lane = tid & 63, w = tid >> 6;
  const int il = lane & 31, h = lane >> 5;
  const int key = (il >> 1) & 3;        // 16B-slot swizzle key (row = il)
  const int i0 = blockIdx.x * 128, jq = blockIdx.y, b = blockIdx.z;
  const short* phb = phiB + (size_t)b * NPOS * NCI;
  const short* thb = thetaB + (size_t)b * NPOS * NCI;
  const short* gb = gB + (size_t)b * NC * NPOS;
  short* om = omidP + ((size_t)(jq * NB + b)) * NC * NPOS;

  // theta B-frags: col i = i0 + w*32 + il, k-chunk kk*16 + h*8
  bf16x8 tf[8];
  {
    const short* tr = thb + (size_t)(i0 + w * 32 + il) * NCI;
#pragma unroll
    for (int kk = 0; kk < 8; ++kk) tf[kk] = *(const bf16x8*)(tr + kk * 16 + h * 8);
  }
  f32x16 acc[8];
#pragma unroll
  for (int i = 0; i < 8; ++i)
#pragma unroll
    for (int r = 0; r < 16; ++r) acc[i][r] = 0.f;

  int4 rphi[2], rg[4];
  const int NT = 32;                    // 32 j-tiles of 32 per quarter
  const int jbase = jq * 32;
#define ATTN_LOAD(jt)                                                          \
  { _Pragma("unroll") for (int r = 0; r < 2; ++r) {                            \
      int s = tid + r * 256; int row = s >> 4, c = s & 15;                     \
      rphi[r] = *(const int4*)(phb + (size_t)((jbase + (jt)) * 32 + row) * NCI + c * 8); } \
    _Pragma("unroll") for (int r = 0; r < 4; ++r) {                            \
      int s = tid + r * 256; int cc = s >> 2, c4 = s & 3;                      \
      rg[r] = *(const int4*)(gb + (size_t)cc * NPOS + (jbase + (jt)) * 32 + c4 * 8); } }
#define ATTN_WRITE(buf)                                                        \
  { _Pragma("unroll") for (int r = 0; r < 2; ++r) {                            \
      int s = tid + r * 256; int row = s >> 4, c = s & 15;                     \
      *(int4*)(&phiT[buf][row * 128 + ((c ^ (row & 7)) * 8)]) = rphi[r]; }     \
    _Pragma("unroll") for (int r = 0; r < 4; ++r) {                            \
      int s = tid + r * 256; int cc = s >> 2, c4 = s & 3;                      \
      *(int4*)(&gT[buf][cc * 32 + ((c4 ^ ((cc >> 1) & 3)) * 8)]) = rg[r]; } }
  ATTN_LOAD(0); ATTN_WRITE(0); __syncthreads();
  int cur = 0;
  for (int jt = 0; jt < NT; ++jt) {
    if (jt + 1 < NT) ATTN_LOAD(jt + 1);
    {
      const short* PH = &phiT[cur][0];
      short* PW = &pT[w][0];
      // ---- S^T: 32 j x 32 i, K=128 via 8 mfma 32x32x16 ----
      f32x16 s16;
#pragma unroll
      for (int r = 0; r < 16; ++r) s16[r] = 0.f;
      const int swp = il & 7;           // phi chunk swizzle (row = j = il)
#pragma unroll
      for (int kk = 0; kk < 8; ++kk) {
        bf16x8 a = *(const bf16x8*)(PH + il * 128 + (((2 * kk + h) ^ swp) * 8));
        s16 = __builtin_amdgcn_mfma_f32_32x32x16_bf16(a, tf[kk], s16, 0, 0, 0);
      }
      // lane holds S^T[j=(r&3)+8*(r>>2)+4h][i = i0+w*32+il]; P = exp(S)
      // write P[i=il][j] : slot g2 (j in [8g2,8g2+8)), 8B half h
#pragma unroll
      for (int g2 = 0; g2 < 4; ++g2) {
        unsigned short p0 = f2bf(__expf(s16[4 * g2 + 0]));
        unsigned short p1 = f2bf(__expf(s16[4 * g2 + 1]));
        unsigned short p2 = f2bf(__expf(s16[4 * g2 + 2]));
        unsigned short p3 = f2bf(__expf(s16[4 * g2 + 3]));
        unsigned int lo = (unsigned int)p0 | ((unsigned int)p1 << 16);
        unsigned int hi2 = (unsigned int)p2 | ((unsigned int)p3 << 16);
        *(uint2*)(PW + il * 32 + ((g2 ^ key) * 8) + 4 * h) = make_uint2(lo, hi2);
      }
      // ---- PV: wave's 32 i x all 256 cc ----
      const short* GT = &gT[cur][0];
      bf16x8 pa[2];
#pragma unroll
      for (int jh2 = 0; jh2 < 2; ++jh2)
        pa[jh2] = *(const bf16x8*)(PW + il * 32 + (((2 * jh2 + h) ^ key) * 8));
#pragma unroll
      for (int ct = 0; ct < 8; ++ct) {
#pragma unroll
        for (int jh2 = 0; jh2 < 2; ++jh2) {
          bf16x8 bg = *(const bf16x8*)(GT + (ct * 32 + il) * 32 + (((2 * jh2 + h) ^ key) * 8));
          acc[ct] = __builtin_amdgcn_mfma_f32_32x32x16_bf16(pa[jh2], bg, acc[ct], 0, 0, 0);
        }
      }
    }
    if (jt + 1 < NT) ATTN_WRITE(cur ^ 1);
    __syncthreads();
    cur ^= 1;
  }
  // store bf16: acc[ct]: cc = ct*32+il, i = i0+w*32 + (r&3)+8*(r>>2)+4h
#pragma unroll
  for (int ct = 0; ct < 8; ++ct)
#pragma unroll
    for (int g2 = 0; g2 < 4; ++g2) {
      __align__(8) short pv[4];
#pragma unroll
      for (int e = 0; e < 4; ++e) pv[e] = (short)f2bf(acc[ct][4 * g2 + e]);
      size_t o = (size_t)(ct * 32 + il) * NPOS + i0 + w * 32 + 8 * g2 + 4 * h;
      *(uint2*)(om + o) = *(const uint2*)pv;
    }
#undef ATTN_LOAD
#undef ATTN_WRITE
}

extern "C" void kernel_launch(void* const* d_in, const int* in_sizes, int n_in,
                              void* d_out, int out_size, void* d_ws, size_t ws_size,
                              hipStream_t stream) {
  (void)in_sizes; (void)n_in; (void)out_size; (void)ws_size;
  const float* x0      = (const float*)d_in[0];
  const float* x       = (const float*)d_in[1];
  const float* x_dsm   = (const float*)d_in[2];
  const float* w_phi   = (const float*)d_in[3];
  const float* w_theta = (const float*)d_in[4];
  const float* w_g     = (const float*)d_in[5];
  const float* w_mask  = (const float*)d_in[6];
  float* outp = (float*)d_out;

  short* sp = (short*)d_ws;
  short* wb_phi   = sp; sp += 32768;
  short* wb_theta = sp; sp += 32768;
  short* wb_g     = sp; sp += 131072;
  short* wb_mask  = sp; sp += 131072;
  short* xT   = sp; sp += (size_t)NB * NPOS * NC;          // 8MB
  short* xdT  = sp; sp += (size_t)NB * NPOS * NC;          // 8MB
  short* x0T  = sp; sp += (size_t)NB * NPOS * NC2;         // 16MB
  short* phiB   = sp; sp += (size_t)NB * NPOS * NCI;       // 4MB
  short* thetaB = sp; sp += (size_t)NB * NPOS * NCI;       // 4MB
  short* gBuf   = sp; sp += (size_t)NB * NC * NPOS;        // 8MB
  float* linv = (float*)sp; sp += 2 * (size_t)NB * NPOS;
  float* plsum = (float*)sp;                               // [b][ISPLIT][NPOS]
  short* omidP = xT;       // 4 bf16 partials x 8MB = 32MB, aliases dead xT/xdT/x0T
  short* omidT = phiB;     // 8MB bf16 [b][p][cc], aliases dead phiB/thetaB

  k_cast4<<<dim3(1280), 256, 0, stream>>>(w_phi, wb_phi, 32768,
                                          w_theta, wb_theta, 32768,
                                          w_g, wb_g, 131072,
                                          w_mask, wb_mask, 131072);

  k_tcast_all<<<dim3(64, 16, NB), 256, 0, stream>>>(x, x_dsm, x0, xT, xdT, x0T);

  k_gemm<true, false, false><<<dim3(64, 2, NB), 256, 0, stream>>>(
      wb_phi, xT, phiB, nullptr, nullptr, NC, NCI, 0, (size_t)NPOS * NC, (size_t)NPOS * NCI);
  k_gemm<true, false, false><<<dim3(64, 2, NB), 256, 0, stream>>>(
      wb_theta, xdT, thetaB, nullptr, nullptr, NC, NCI, 0, (size_t)NPOS * NC, (size_t)NPOS * NCI);

  k_lsum<<<dim3(NPOS / 128, ISPLIT, NB), 256, 0, stream>>>(phiB, thetaB, plsum);
  k_lcomb<<<dim3(NB * NPOS / 256), 256, 0, stream>>>(plsum, linv);

  // g[cc][p] = (sum_c x0T[p][c] W_g[cc][c]) * linv[p]   (m=p scaled)
  k_gemm<true, false, true><<<dim3(4, 64, NB), 256, 0, stream>>>(
      x0T, wb_g, gBuf, nullptr, linv, NC2, NPOS, (size_t)NPOS * NC2, 0, (size_t)NC * NPOS);

  k_attn<<<dim3(NPOS / 128, 4, NB), 256, 0, stream>>>(phiB, thetaB, gBuf, omidP);

  k_tcast4<<<dim3(64, 4, NB), 256, 0, stream>>>(omidP, omidT);

  k_gemm<false, true, false><<<dim3(8, 64, NB), 256, 0, stream>>>(
      omidT, wb_mask, outp, x0, nullptr, NC, NPOS, (size_t)NPOS * NC, 0, (size_t)NC2 * NPOS);
}

// Round 22
// 226.840 us; speedup vs baseline: 2.0014x; 1.0120x over previous
//
#include <hip/hip_runtime.h>
#include <math.h>

#define NB 4
#define NC 256
#define NCI 128
#define NC2 512
#define NPOS 4096
#define ISPLIT 8

using bf16x8 = __attribute__((ext_vector_type(8))) short;
using f32x4  = __attribute__((ext_vector_type(4))) float;
using f32x16 = __attribute__((ext_vector_type(16))) float;

__device__ inline unsigned short f2bf(float f) {
  unsigned int u = __float_as_uint(f);
  u = (u + 0x7fffu + ((u >> 16) & 1u)) >> 16;
  return (unsigned short)u;
}
__device__ inline float bf2f(short s) {
  return __uint_as_float(((unsigned int)(unsigned short)s) << 16);
}

// ---------------- cast 4 weight tensors fp32 -> bf16 ----------------
__global__ void k_cast4(const float* __restrict__ s0, short* __restrict__ d0, int n0,
                        const float* __restrict__ s1, short* __restrict__ d1, int n1,
                        const float* __restrict__ s2, short* __restrict__ d2, int n2,
                        const float* __restrict__ s3, short* __restrict__ d3, int n3) {
  int i = blockIdx.x * 256 + threadIdx.x;
  if (i < n0) { d0[i] = (short)f2bf(s0[i]); return; } i -= n0;
  if (i < n1) { d1[i] = (short)f2bf(s1[i]); return; } i -= n1;
  if (i < n2) { d2[i] = (short)f2bf(s2[i]); return; } i -= n2;
  if (i < n3) { d3[i] = (short)f2bf(s3[i]); }
}

// ---------------- fused transpose-cast for x, x_dsm, x0 ----------------
__global__ __launch_bounds__(256) void k_tcast_all(
    const float* __restrict__ x, const float* __restrict__ xdsm,
    const float* __restrict__ x0, short* __restrict__ xT,
    short* __restrict__ xdT, short* __restrict__ x0T) {
  __shared__ float t[64][65];
  const int tid = threadIdx.x;
  const int y = blockIdx.y, c0 = blockIdx.x * 64, b = blockIdx.z;
  const float* in; short* out; int R, r0;
  if (y < 4)      { in = x;    out = xT;  R = NC;  r0 = y * 64; }
  else if (y < 8) { in = xdsm; out = xdT; R = NC;  r0 = (y - 4) * 64; }
  else            { in = x0;   out = x0T; R = NC2; r0 = (y - 8) * 64; }
  const size_t inBs = (size_t)R * NPOS, outBs = (size_t)NPOS * R;
  {
    int r = tid >> 2, cc = (tid & 3) * 16;
    const float* ib = in + (size_t)b * inBs + (size_t)(r0 + r) * NPOS + c0 + cc;
#pragma unroll
    for (int i = 0; i < 4; ++i) {
      float4 v = *(const float4*)(ib + i * 4);
      t[r][cc + i * 4 + 0] = v.x; t[r][cc + i * 4 + 1] = v.y;
      t[r][cc + i * 4 + 2] = v.z; t[r][cc + i * 4 + 3] = v.w;
    }
  }
  __syncthreads();
  {
    int c = tid >> 2, rr = (tid & 3) * 16;
    __align__(16) short v[16];
#pragma unroll
    for (int i = 0; i < 16; ++i) v[i] = (short)f2bf(t[rr + i][c]);
    short* ob = out + (size_t)b * outBs + (size_t)(c0 + c) * R + r0 + rr;
    *(int4*)(ob) = *(const int4*)(v);
    *(int4*)(ob + 8) = *(const int4*)(v + 8);
  }
}

// ---------------- sum 4 bf16 partials [p][b][cc][i] -> transpose [b][i][cc] bf16
__global__ __launch_bounds__(256) void k_tcast4(
    const short* __restrict__ inP, short* __restrict__ out) {
  __shared__ float t[64][65];
  const int tid = threadIdx.x;
  const int r0 = blockIdx.y * 64, c0 = blockIdx.x * 64, b = blockIdx.z;
  {
    int r = tid >> 2, cc = (tid & 3) * 16;
    float tacc[16] = {};
#pragma unroll
    for (int p = 0; p < 4; ++p) {
      const short* ib = inP + ((size_t)p * NB + b) * NC * NPOS +
                        (size_t)(r0 + r) * NPOS + c0 + cc;
      bf16x8 a = *(const bf16x8*)(ib);
      bf16x8 a2 = *(const bf16x8*)(ib + 8);
#pragma unroll
      for (int i = 0; i < 8; ++i) { tacc[i] += bf2f(a[i]); tacc[8 + i] += bf2f(a2[i]); }
    }
#pragma unroll
    for (int i = 0; i < 16; ++i) t[r][cc + i] = tacc[i];
  }
  __syncthreads();
  {
    int c = tid >> 2, rr = (tid & 3) * 16;
    __align__(16) short v[16];
#pragma unroll
    for (int i = 0; i < 16; ++i) v[i] = (short)f2bf(t[rr + i][c]);
    short* ob = out + (size_t)b * (size_t)NPOS * NC + (size_t)(c0 + c) * NC + r0 + rr;
    *(int4*)(ob) = *(const int4*)(v);
    *(int4*)(ob + 8) = *(const int4*)(v + 8);
  }
}

// ---------------- generic bf16 MFMA GEMM ----------------
// SCALE_M: multiply output by scaleM[b*NPOS + m]. DUAL: grid.z in [0,2*NB),
// z>=NB selects (A2,B2,out2) -- used to merge phi+theta GEMMs.
template<bool OUT_BF16, bool HAS_RES, bool SCALE_M, bool DUAL>
__global__ __launch_bounds__(256, 4) void k_gemm(
    const short* __restrict__ A, const short* __restrict__ B,
    void* __restrict__ outv, const float* __restrict__ res,
    const float* __restrict__ scaleM,
    const short* __restrict__ A2, const short* __restrict__ B2,
    void* __restrict__ outv2,
    int K, int sN, size_t aBs, size_t bBs, size_t oBs) {
  __shared__ short As[2][64 * 64];
  __shared__ short Bs_[2][64 * 64];
  const int tid = threadIdx.x, lane = tid & 63, w = tid >> 6;
  const int x = lane & 15, q = lane >> 4;
  const int wm = (w & 1) * 32, wn = (w >> 1) * 32;
  int b = blockIdx.z;
  if (DUAL && b >= NB) {
    A = A2; B = B2; outv = outv2; b -= NB;
  }
  const int n0 = blockIdx.x * 64, m0 = blockIdx.y * 64;
  const short* Ab = A + (size_t)b * aBs + (size_t)m0 * K;
  const short* Bb = B + (size_t)b * bBs + (size_t)n0 * K;
  const int r = tid >> 2, cth = tid & 3;
  f32x4 acc[2][2];
  acc[0][0] = acc[0][1] = acc[1][0] = acc[1][1] = (f32x4){0.f, 0.f, 0.f, 0.f};
  int4 ra[2], rb[2];
  const int NK = K >> 6;
#define GLOAD(kt)                                                              \
  { _Pragma("unroll") for (int i = 0; i < 2; ++i) {                            \
      ra[i] = *(const int4*)(Ab + (size_t)r * K + (kt) * 64 + (cth + i * 4) * 8); \
      rb[i] = *(const int4*)(Bb + (size_t)r * K + (kt) * 64 + (cth + i * 4) * 8); } }
#define GWRITE(buf)                                                            \
  { _Pragma("unroll") for (int i = 0; i < 2; ++i) {                            \
      *(int4*)(&As[buf][r * 64 + (((cth + i * 4) ^ (r & 7)) * 8)]) = ra[i];    \
      *(int4*)(&Bs_[buf][r * 64 + (((cth + i * 4) ^ (r & 7)) * 8)]) = rb[i]; } }
  GLOAD(0); GWRITE(0); __syncthreads();
  int cur = 0;
  for (int kt = 0; kt < NK; ++kt) {
    if (kt + 1 < NK) GLOAD(kt + 1);
    bf16x8 af[2][2], bfr[2][2];
#pragma unroll
    for (int ms = 0; ms < 2; ++ms) {
      int rowm = wm + ms * 16 + x;
#pragma unroll
      for (int ks = 0; ks < 2; ++ks)
        af[ms][ks] = *(const bf16x8*)(&As[cur][rowm * 64 + (((ks * 4 + q) ^ (rowm & 7)) * 8)]);
    }
#pragma unroll
    for (int ns = 0; ns < 2; ++ns) {
      int rown = wn + ns * 16 + x;
#pragma unroll
      for (int ks = 0; ks < 2; ++ks)
        bfr[ns][ks] = *(const bf16x8*)(&Bs_[cur][rown * 64 + (((ks * 4 + q) ^ (rown & 7)) * 8)]);
    }
#pragma unroll
    for (int ms = 0; ms < 2; ++ms)
#pragma unroll
      for (int ns = 0; ns < 2; ++ns)
#pragma unroll
        for (int ks = 0; ks < 2; ++ks)
          acc[ms][ns] = __builtin_amdgcn_mfma_f32_16x16x32_bf16(
              af[ms][ks], bfr[ns][ks], acc[ms][ns], 0, 0, 0);
    if (kt + 1 < NK) GWRITE(cur ^ 1);
    __syncthreads();
    cur ^= 1;
  }
#pragma unroll
  for (int ms = 0; ms < 2; ++ms)
#pragma unroll
    for (int ns = 0; ns < 2; ++ns) {
      int n = n0 + wn + ns * 16 + x;
      int m = m0 + wm + ms * 16 + q * 4;
      size_t off = (size_t)b * oBs + (size_t)n * sN + m;
      float4 sv = {1.f, 1.f, 1.f, 1.f};
      if (SCALE_M) sv = *(const float4*)(scaleM + ((size_t)b << 12) + m);
      if (OUT_BF16) {
        __align__(8) short pv[4];
        pv[0] = (short)f2bf(acc[ms][ns][0] * sv.x);
        pv[1] = (short)f2bf(acc[ms][ns][1] * sv.y);
        pv[2] = (short)f2bf(acc[ms][ns][2] * sv.z);
        pv[3] = (short)f2bf(acc[ms][ns][3] * sv.w);
        *(uint2*)((short*)outv + off) = *(const uint2*)pv;
      } else {
        float4 v = {acc[ms][ns][0], acc[ms][ns][1], acc[ms][ns][2], acc[ms][ns][3]};
        if (HAS_RES) {
          float4 rv = *(const float4*)(res + off);
          v.x += rv.x; v.y += rv.y; v.z += rv.z; v.w += rv.w;
        }
        *(float4*)((float*)outv + off) = v;
      }
    }
#undef GLOAD
#undef GWRITE
}

// ---------------- partial l[j], 32x32 MFMA: plsum[b][iy][j] ----------------
__global__ __launch_bounds__(256, 4) void k_lsum(
    const short* __restrict__ phiB, const short* __restrict__ thetaB,
    float* __restrict__ plsum) {
  __shared__ short thT[2][32 * 128];   // 8KB each, chunk-swizzled ^(row&7)
  const int tid = threadIdx.x, lane = tid & 63, w = tid >> 6;
  const int il = lane & 31, h = lane >> 5;
  const int j0 = blockIdx.x * 128, iy = blockIdx.y, b = blockIdx.z;
  const short* phb = phiB + (size_t)b * NPOS * NCI;
  const short* thb = thetaB + (size_t)b * NPOS * NCI + (size_t)iy * (NPOS / ISPLIT) * NCI;
  bf16x8 pf[8];
  {
    const short* pr = phb + (size_t)(j0 + w * 32 + il) * NCI;
#pragma unroll
    for (int kk = 0; kk < 8; ++kk) pf[kk] = *(const bf16x8*)(pr + kk * 16 + h * 8);
  }
  float lsum = 0.f;
  int4 rt[2];
  const int NIT = NPOS / ISPLIT / 32;   // 16
#define LSUM_LOAD(it)                                                         \
  { _Pragma("unroll") for (int r = 0; r < 2; ++r) {                           \
      int s = tid + r * 256; int row = s >> 4, c = s & 15;                    \
      rt[r] = *(const int4*)(thb + (size_t)((it) * 32 + row) * NCI + c * 8); } }
#define LSUM_WRITE(buf)                                                       \
  { _Pragma("unroll") for (int r = 0; r < 2; ++r) {                           \
      int s = tid + r * 256; int row = s >> 4, c = s & 15;                    \
      *(int4*)(&thT[buf][row * 128 + ((c ^ (row & 7)) * 8)]) = rt[r]; } }
  LSUM_LOAD(0); LSUM_WRITE(0); __syncthreads();
  int cur = 0;
  const int swz = il & 7;
  for (int it = 0; it < NIT; ++it) {
    if (it + 1 < NIT) LSUM_LOAD(it + 1);
    f32x16 s16;
#pragma unroll
    for (int r = 0; r < 16; ++r) s16[r] = 0.f;
#pragma unroll
    for (int kk = 0; kk < 8; ++kk) {
      bf16x8 a = *(const bf16x8*)(&thT[cur][il * 128 + (((2 * kk + h) ^ swz) * 8)]);
      s16 = __builtin_amdgcn_mfma_f32_32x32x16_bf16(a, pf[kk], s16, 0, 0, 0);
    }
#pragma unroll
    for (int r = 0; r < 16; ++r) lsum += __expf(s16[r]);
    if (it + 1 < NIT) LSUM_WRITE(cur ^ 1);
    __syncthreads();
    cur ^= 1;
  }
  lsum += __shfl_xor(lsum, 32);
  if (h == 0)
    plsum[((size_t)(b * ISPLIT + iy) << 12) + j0 + w * 32 + il] = lsum;
#undef LSUM_LOAD
#undef LSUM_WRITE
}

// ---------------- combine partials -> linv ----------------
__global__ void k_lcomb(const float* __restrict__ plsum, float* __restrict__ linv) {
  int i = blockIdx.x * 256 + threadIdx.x;   // NB*NPOS
  int b = i >> 12, j = i & (NPOS - 1);
  float s = 0.f;
#pragma unroll
  for (int t = 0; t < ISPLIT; ++t) s += plsum[((size_t)(b * ISPLIT + t) << 12) + j];
  linv[i] = 1.0f / s;
}

// ---------------- attention, 32x32x16 MFMA (R19-verified) ----------------
__global__ __launch_bounds__(256, 2) void k_attn(
    const short* __restrict__ phiB, const short* __restrict__ thetaB,
    const short* __restrict__ gB, short* __restrict__ omidP) {
  __shared__ short phiT[2][32 * 128];   // 8KB each, chunk-swizzled ^(row&7)
  __shared__ short gT[2][256 * 32];     // 16KB each, slot-swizzled ^((row>>1)&3)
  __shared__ short pT[4][32 * 32];      // 2KB per wave, slot-swizzled
  const int tid = threadIdx.x, lane = tid & 63, w = tid >> 6;
  const int il = lane & 31, h = lane >> 5;
  const int key = (il >> 1) & 3;        // 16B-slot swizzle key (row = il)
  const int i0 = blockIdx.x * 128, jq = blockIdx.y, b = blockIdx.z;
  const short* phb = phiB + (size_t)b * NPOS * NCI;
  const short* thb = thetaB + (size_t)b * NPOS * NCI;
  const short* gb = gB + (size_t)b * NC * NPOS;
  short* om = omidP + ((size_t)(jq * NB + b)) * NC * NPOS;

  bf16x8 tf[8];
  {
    const short* tr = thb + (size_t)(i0 + w * 32 + il) * NCI;
#pragma unroll
    for (int kk = 0; kk < 8; ++kk) tf[kk] = *(const bf16x8*)(tr + kk * 16 + h * 8);
  }
  f32x16 acc[8];
#pragma unroll
  for (int i = 0; i < 8; ++i)
#pragma unroll
    for (int r = 0; r < 16; ++r) acc[i][r] = 0.f;

  int4 rphi[2], rg[4];
  const int NT = 32;                    // 32 j-tiles of 32 per quarter
  const int jbase = jq * 32;
#define ATTN_LOAD(jt)                                                          \
  { _Pragma("unroll") for (int r = 0; r < 2; ++r) {                            \
      int s = tid + r * 256; int row = s >> 4, c = s & 15;                     \
      rphi[r] = *(const int4*)(phb + (size_t)((jbase + (jt)) * 32 + row) * NCI + c * 8); } \
    _Pragma("unroll") for (int r = 0; r < 4; ++r) {                            \
      int s = tid + r * 256; int cc = s >> 2, c4 = s & 3;                      \
      rg[r] = *(const int4*)(gb + (size_t)cc * NPOS + (jbase + (jt)) * 32 + c4 * 8); } }
#define ATTN_WRITE(buf)                                                        \
  { _Pragma("unroll") for (int r = 0; r < 2; ++r) {                            \
      int s = tid + r * 256; int row = s >> 4, c = s & 15;                     \
      *(int4*)(&phiT[buf][row * 128 + ((c ^ (row & 7)) * 8)]) = rphi[r]; }     \
    _Pragma("unroll") for (int r = 0; r < 4; ++r) {                            \
      int s = tid + r * 256; int cc = s >> 2, c4 = s & 3;                      \
      *(int4*)(&gT[buf][cc * 32 + ((c4 ^ ((cc >> 1) & 3)) * 8)]) = rg[r]; } }
  ATTN_LOAD(0); ATTN_WRITE(0); __syncthreads();
  int cur = 0;
  for (int jt = 0; jt < NT; ++jt) {
    if (jt + 1 < NT) ATTN_LOAD(jt + 1);
    {
      const short* PH = &phiT[cur][0];
      short* PW = &pT[w][0];
      // ---- S^T: 32 j x 32 i, K=128 via 8 mfma 32x32x16 ----
      f32x16 s16;
#pragma unroll
      for (int r = 0; r < 16; ++r) s16[r] = 0.f;
      const int swp = il & 7;           // phi chunk swizzle (row = j = il)
#pragma unroll
      for (int kk = 0; kk < 8; ++kk) {
        bf16x8 a = *(const bf16x8*)(PH + il * 128 + (((2 * kk + h) ^ swp) * 8));
        s16 = __builtin_amdgcn_mfma_f32_32x32x16_bf16(a, tf[kk], s16, 0, 0, 0);
      }
      // lane holds S^T[j=(r&3)+8*(r>>2)+4h][i = i0+w*32+il]; P = exp(S)
#pragma unroll
      for (int g2 = 0; g2 < 4; ++g2) {
        unsigned short p0 = f2bf(__expf(s16[4 * g2 + 0]));
        unsigned short p1 = f2bf(__expf(s16[4 * g2 + 1]));
        unsigned short p2 = f2bf(__expf(s16[4 * g2 + 2]));
        unsigned short p3 = f2bf(__expf(s16[4 * g2 + 3]));
        unsigned int lo = (unsigned int)p0 | ((unsigned int)p1 << 16);
        unsigned int hi2 = (unsigned int)p2 | ((unsigned int)p3 << 16);
        *(uint2*)(PW + il * 32 + ((g2 ^ key) * 8) + 4 * h) = make_uint2(lo, hi2);
      }
      // ---- PV: wave's 32 i x all 256 cc ----
      const short* GT = &gT[cur][0];
      bf16x8 pa[2];
#pragma unroll
      for (int jh2 = 0; jh2 < 2; ++jh2)
        pa[jh2] = *(const bf16x8*)(PW + il * 32 + (((2 * jh2 + h) ^ key) * 8));
#pragma unroll
      for (int ct = 0; ct < 8; ++ct) {
#pragma unroll
        for (int jh2 = 0; jh2 < 2; ++jh2) {
          bf16x8 bg = *(const bf16x8*)(GT + (ct * 32 + il) * 32 + (((2 * jh2 + h) ^ key) * 8));
          acc[ct] = __builtin_amdgcn_mfma_f32_32x32x16_bf16(pa[jh2], bg, acc[ct], 0, 0, 0);
        }
      }
    }
    if (jt + 1 < NT) ATTN_WRITE(cur ^ 1);
    __syncthreads();
    cur ^= 1;
  }
#pragma unroll
  for (int ct = 0; ct < 8; ++ct)
#pragma unroll
    for (int g2 = 0; g2 < 4; ++g2) {
      __align__(8) short pv[4];
#pragma unroll
      for (int e = 0; e < 4; ++e) pv[e] = (short)f2bf(acc[ct][4 * g2 + e]);
      size_t o = (size_t)(ct * 32 + il) * NPOS + i0 + w * 32 + 8 * g2 + 4 * h;
      *(uint2*)(om + o) = *(const uint2*)pv;
    }
#undef ATTN_LOAD
#undef ATTN_WRITE
}

extern "C" void kernel_launch(void* const* d_in, const int* in_sizes, int n_in,
                              void* d_out, int out_size, void* d_ws, size_t ws_size,
                              hipStream_t stream) {
  (void)in_sizes; (void)n_in; (void)out_size; (void)ws_size;
  const float* x0      = (const float*)d_in[0];
  const float* x       = (const float*)d_in[1];
  const float* x_dsm   = (const float*)d_in[2];
  const float* w_phi   = (const float*)d_in[3];
  const float* w_theta = (const float*)d_in[4];
  const float* w_g     = (const float*)d_in[5];
  const float* w_mask  = (const float*)d_in[6];
  float* outp = (float*)d_out;

  short* sp = (short*)d_ws;
  short* wb_phi   = sp; sp += 32768;
  short* wb_theta = sp; sp += 32768;
  short* wb_g     = sp; sp += 131072;
  short* wb_mask  = sp; sp += 131072;
  short* xT   = sp; sp += (size_t)NB * NPOS * NC;          // 8MB
  short* xdT  = sp; sp += (size_t)NB * NPOS * NC;          // 8MB
  short* x0T  = sp; sp += (size_t)NB * NPOS * NC2;         // 16MB
  short* phiB   = sp; sp += (size_t)NB * NPOS * NCI;       // 4MB
  short* thetaB = sp; sp += (size_t)NB * NPOS * NCI;       // 4MB
  short* gBuf   = sp; sp += (size_t)NB * NC * NPOS;        // 8MB
  float* linv = (float*)sp; sp += 2 * (size_t)NB * NPOS;
  float* plsum = (float*)sp;                               // [b][ISPLIT][NPOS]
  short* omidP = xT;       // 4 bf16 partials x 8MB = 32MB, aliases dead xT/xdT/x0T
  short* omidT = phiB;     // 8MB bf16 [b][p][cc], aliases dead phiB/thetaB

  k_cast4<<<dim3(1280), 256, 0, stream>>>(w_phi, wb_phi, 32768,
                                          w_theta, wb_theta, 32768,
                                          w_g, wb_g, 131072,
                                          w_mask, wb_mask, 131072);

  k_tcast_all<<<dim3(64, 16, NB), 256, 0, stream>>>(x, x_dsm, x0, xT, xdT, x0T);

  // phi + theta in one dispatch (z<NB: phi from xT; z>=NB: theta from xdT)
  k_gemm<true, false, false, true><<<dim3(64, 2, 2 * NB), 256, 0, stream>>>(
      wb_phi, xT, phiB, nullptr, nullptr, wb_theta, xdT, thetaB,
      NC, NCI, 0, (size_t)NPOS * NC, (size_t)NPOS * NCI);

  k_lsum<<<dim3(NPOS / 128, ISPLIT, NB), 256, 0, stream>>>(phiB, thetaB, plsum);
  k_lcomb<<<dim3(NB * NPOS / 256), 256, 0, stream>>>(plsum, linv);

  // g[cc][p] = (sum_c x0T[p][c] W_g[cc][c]) * linv[p]   (m=p scaled)
  k_gemm<true, false, true, false><<<dim3(4, 64, NB), 256, 0, stream>>>(
      x0T, wb_g, gBuf, nullptr, linv, nullptr, nullptr, nullptr,
      NC2, NPOS, (size_t)NPOS * NC2, 0, (size_t)NC * NPOS);

  k_attn<<<dim3(NPOS / 128, 4, NB), 256, 0, stream>>>(phiB, thetaB, gBuf, omidP);

  k_tcast4<<<dim3(64, 4, NB), 256, 0, stream>>>(omidP, omidT);

  k_gemm<false, true, false, false><<<dim3(8, 64, NB), 256, 0, stream>>>(
      omidT, wb_mask, outp, x0, nullptr, nullptr, nullptr, nullptr,
      NC, NPOS, (size_t)NPOS * NC, 0, (size_t)NC2 * NPOS);
}

// Round 23
// 222.257 us; speedup vs baseline: 2.0427x; 1.0206x over previous
//
#include <hip/hip_runtime.h>
#include <math.h>

#define NB 4
#define NC 256
#define NCI 128
#define NC2 512
#define NPOS 4096
#define ISPLIT 8

using bf16x8 = __attribute__((ext_vector_type(8))) short;
using f32x4  = __attribute__((ext_vector_type(4))) float;
using f32x16 = __attribute__((ext_vector_type(16))) float;

__device__ inline unsigned short f2bf(float f) {
  unsigned int u = __float_as_uint(f);
  u = (u + 0x7fffu + ((u >> 16) & 1u)) >> 16;
  return (unsigned short)u;
}
__device__ inline float bf2f(short s) {
  return __uint_as_float(((unsigned int)(unsigned short)s) << 16);
}

// ------- fused transpose-cast for x, x_dsm, x0  (+ y==16: weight cast) -------
__global__ __launch_bounds__(256) void k_tcast_all(
    const float* __restrict__ x, const float* __restrict__ xdsm,
    const float* __restrict__ x0, short* __restrict__ xT,
    short* __restrict__ xdT, short* __restrict__ x0T,
    const float* __restrict__ wsrc0, short* __restrict__ wdst0,   // 32768
    const float* __restrict__ wsrc1, short* __restrict__ wdst1,   // 32768
    const float* __restrict__ wsrc2, short* __restrict__ wdst2,   // 131072
    const float* __restrict__ wsrc3, short* __restrict__ wdst3) { // 131072
  __shared__ float t[64][65];
  const int tid = threadIdx.x;
  const int y = blockIdx.y, c0 = blockIdx.x * 64, b = blockIdx.z;
  if (y == 16) {
    // weight cast: 327680 elems over 64*NB blocks * 256 threads * 5 elems
    int g = ((b * 64 + blockIdx.x) * 256 + tid) * 5;
#pragma unroll
    for (int k = 0; k < 5; ++k) {
      int i = g + k;
      if (i < 32768) { wdst0[i] = (short)f2bf(wsrc0[i]); continue; }
      i -= 32768;
      if (i < 32768) { wdst1[i] = (short)f2bf(wsrc1[i]); continue; }
      i -= 32768;
      if (i < 131072) { wdst2[i] = (short)f2bf(wsrc2[i]); continue; }
      i -= 131072;
      wdst3[i] = (short)f2bf(wsrc3[i]);
    }
    return;
  }
  const float* in; short* out; int R, r0;
  if (y < 4)      { in = x;    out = xT;  R = NC;  r0 = y * 64; }
  else if (y < 8) { in = xdsm; out = xdT; R = NC;  r0 = (y - 4) * 64; }
  else            { in = x0;   out = x0T; R = NC2; r0 = (y - 8) * 64; }
  const size_t inBs = (size_t)R * NPOS, outBs = (size_t)NPOS * R;
  {
    int r = tid >> 2, cc = (tid & 3) * 16;
    const float* ib = in + (size_t)b * inBs + (size_t)(r0 + r) * NPOS + c0 + cc;
#pragma unroll
    for (int i = 0; i < 4; ++i) {
      float4 v = *(const float4*)(ib + i * 4);
      t[r][cc + i * 4 + 0] = v.x; t[r][cc + i * 4 + 1] = v.y;
      t[r][cc + i * 4 + 2] = v.z; t[r][cc + i * 4 + 3] = v.w;
    }
  }
  __syncthreads();
  {
    int c = tid >> 2, rr = (tid & 3) * 16;
    __align__(16) short v[16];
#pragma unroll
    for (int i = 0; i < 16; ++i) v[i] = (short)f2bf(t[rr + i][c]);
    short* ob = out + (size_t)b * outBs + (size_t)(c0 + c) * R + r0 + rr;
    *(int4*)(ob) = *(const int4*)(v);
    *(int4*)(ob + 8) = *(const int4*)(v + 8);
  }
}

// ---------------- sum 4 bf16 partials [p][b][cc][i] -> transpose [b][i][cc] bf16
__global__ __launch_bounds__(256) void k_tcast4(
    const short* __restrict__ inP, short* __restrict__ out) {
  __shared__ float t[64][65];
  const int tid = threadIdx.x;
  const int r0 = blockIdx.y * 64, c0 = blockIdx.x * 64, b = blockIdx.z;
  {
    int r = tid >> 2, cc = (tid & 3) * 16;
    float tacc[16] = {};
#pragma unroll
    for (int p = 0; p < 4; ++p) {
      const short* ib = inP + ((size_t)p * NB + b) * NC * NPOS +
                        (size_t)(r0 + r) * NPOS + c0 + cc;
      bf16x8 a = *(const bf16x8*)(ib);
      bf16x8 a2 = *(const bf16x8*)(ib + 8);
#pragma unroll
      for (int i = 0; i < 8; ++i) { tacc[i] += bf2f(a[i]); tacc[8 + i] += bf2f(a2[i]); }
    }
#pragma unroll
    for (int i = 0; i < 16; ++i) t[r][cc + i] = tacc[i];
  }
  __syncthreads();
  {
    int c = tid >> 2, rr = (tid & 3) * 16;
    __align__(16) short v[16];
#pragma unroll
    for (int i = 0; i < 16; ++i) v[i] = (short)f2bf(t[rr + i][c]);
    short* ob = out + (size_t)b * (size_t)NPOS * NC + (size_t)(c0 + c) * NC + r0 + rr;
    *(int4*)(ob) = *(const int4*)(v);
    *(int4*)(ob + 8) = *(const int4*)(v + 8);
  }
}

// ---------------- generic bf16 MFMA GEMM ----------------
// SCALE_M: multiply output by 1/sum_t plsum[b][t][m] (linv computed inline).
// DUAL: grid.z in [0,2*NB), z>=NB selects (A2,B2,out2).
template<bool OUT_BF16, bool HAS_RES, bool SCALE_M, bool DUAL>
__global__ __launch_bounds__(256, 4) void k_gemm(
    const short* __restrict__ A, const short* __restrict__ B,
    void* __restrict__ outv, const float* __restrict__ res,
    const float* __restrict__ plsumP,
    const short* __restrict__ A2, const short* __restrict__ B2,
    void* __restrict__ outv2,
    int K, int sN, size_t aBs, size_t bBs, size_t oBs) {
  __shared__ short As[2][64 * 64];
  __shared__ short Bs_[2][64 * 64];
  const int tid = threadIdx.x, lane = tid & 63, w = tid >> 6;
  const int x = lane & 15, q = lane >> 4;
  const int wm = (w & 1) * 32, wn = (w >> 1) * 32;
  int b = blockIdx.z;
  if (DUAL && b >= NB) {
    A = A2; B = B2; outv = outv2; b -= NB;
  }
  const int n0 = blockIdx.x * 64, m0 = blockIdx.y * 64;
  const short* Ab = A + (size_t)b * aBs + (size_t)m0 * K;
  const short* Bb = B + (size_t)b * bBs + (size_t)n0 * K;
  const int r = tid >> 2, cth = tid & 3;
  f32x4 acc[2][2];
  acc[0][0] = acc[0][1] = acc[1][0] = acc[1][1] = (f32x4){0.f, 0.f, 0.f, 0.f};
  int4 ra[2], rb[2];
  const int NK = K >> 6;
#define GLOAD(kt)                                                              \
  { _Pragma("unroll") for (int i = 0; i < 2; ++i) {                            \
      ra[i] = *(const int4*)(Ab + (size_t)r * K + (kt) * 64 + (cth + i * 4) * 8); \
      rb[i] = *(const int4*)(Bb + (size_t)r * K + (kt) * 64 + (cth + i * 4) * 8); } }
#define GWRITE(buf)                                                            \
  { _Pragma("unroll") for (int i = 0; i < 2; ++i) {                            \
      *(int4*)(&As[buf][r * 64 + (((cth + i * 4) ^ (r & 7)) * 8)]) = ra[i];    \
      *(int4*)(&Bs_[buf][r * 64 + (((cth + i * 4) ^ (r & 7)) * 8)]) = rb[i]; } }
  GLOAD(0); GWRITE(0); __syncthreads();
  int cur = 0;
  for (int kt = 0; kt < NK; ++kt) {
    if (kt + 1 < NK) GLOAD(kt + 1);
    bf16x8 af[2][2], bfr[2][2];
#pragma unroll
    for (int ms = 0; ms < 2; ++ms) {
      int rowm = wm + ms * 16 + x;
#pragma unroll
      for (int ks = 0; ks < 2; ++ks)
        af[ms][ks] = *(const bf16x8*)(&As[cur][rowm * 64 + (((ks * 4 + q) ^ (rowm & 7)) * 8)]);
    }
#pragma unroll
    for (int ns = 0; ns < 2; ++ns) {
      int rown = wn + ns * 16 + x;
#pragma unroll
      for (int ks = 0; ks < 2; ++ks)
        bfr[ns][ks] = *(const bf16x8*)(&Bs_[cur][rown * 64 + (((ks * 4 + q) ^ (rown & 7)) * 8)]);
    }
#pragma unroll
    for (int ms = 0; ms < 2; ++ms)
#pragma unroll
      for (int ns = 0; ns < 2; ++ns)
#pragma unroll
        for (int ks = 0; ks < 2; ++ks)
          acc[ms][ns] = __builtin_amdgcn_mfma_f32_16x16x32_bf16(
              af[ms][ks], bfr[ns][ks], acc[ms][ns], 0, 0, 0);
    if (kt + 1 < NK) GWRITE(cur ^ 1);
    __syncthreads();
    cur ^= 1;
  }
  float4 sv[2] = {{1.f, 1.f, 1.f, 1.f}, {1.f, 1.f, 1.f, 1.f}};
  if (SCALE_M) {
#pragma unroll
    for (int ms = 0; ms < 2; ++ms) {
      int m = m0 + wm + ms * 16 + q * 4;
      float4 s = {0.f, 0.f, 0.f, 0.f};
#pragma unroll
      for (int t = 0; t < ISPLIT; ++t) {
        float4 pv = *(const float4*)(plsumP + ((size_t)(b * ISPLIT + t) << 12) + m);
        s.x += pv.x; s.y += pv.y; s.z += pv.z; s.w += pv.w;
      }
      sv[ms].x = 1.0f / s.x; sv[ms].y = 1.0f / s.y;
      sv[ms].z = 1.0f / s.z; sv[ms].w = 1.0f / s.w;
    }
  }
#pragma unroll
  for (int ms = 0; ms < 2; ++ms)
#pragma unroll
    for (int ns = 0; ns < 2; ++ns) {
      int n = n0 + wn + ns * 16 + x;
      int m = m0 + wm + ms * 16 + q * 4;
      size_t off = (size_t)b * oBs + (size_t)n * sN + m;
      if (OUT_BF16) {
        __align__(8) short pv[4];
        pv[0] = (short)f2bf(acc[ms][ns][0] * sv[ms].x);
        pv[1] = (short)f2bf(acc[ms][ns][1] * sv[ms].y);
        pv[2] = (short)f2bf(acc[ms][ns][2] * sv[ms].z);
        pv[3] = (short)f2bf(acc[ms][ns][3] * sv[ms].w);
        *(uint2*)((short*)outv + off) = *(const uint2*)pv;
      } else {
        float4 v = {acc[ms][ns][0], acc[ms][ns][1], acc[ms][ns][2], acc[ms][ns][3]};
        if (HAS_RES) {
          float4 rv = *(const float4*)(res + off);
          v.x += rv.x; v.y += rv.y; v.z += rv.z; v.w += rv.w;
        }
        *(float4*)((float*)outv + off) = v;
      }
    }
#undef GLOAD
#undef GWRITE
}

// ---------------- partial l[j], 32x32 MFMA: plsum[b][iy][j] ----------------
__global__ __launch_bounds__(256, 4) void k_lsum(
    const short* __restrict__ phiB, const short* __restrict__ thetaB,
    float* __restrict__ plsum) {
  __shared__ short thT[2][32 * 128];   // 8KB each, chunk-swizzled ^(row&7)
  const int tid = threadIdx.x, lane = tid & 63, w = tid >> 6;
  const int il = lane & 31, h = lane >> 5;
  const int j0 = blockIdx.x * 128, iy = blockIdx.y, b = blockIdx.z;
  const short* phb = phiB + (size_t)b * NPOS * NCI;
  const short* thb = thetaB + (size_t)b * NPOS * NCI + (size_t)iy * (NPOS / ISPLIT) * NCI;
  bf16x8 pf[8];
  {
    const short* pr = phb + (size_t)(j0 + w * 32 + il) * NCI;
#pragma unroll
    for (int kk = 0; kk < 8; ++kk) pf[kk] = *(const bf16x8*)(pr + kk * 16 + h * 8);
  }
  float lsum = 0.f;
  int4 rt[2];
  const int NIT = NPOS / ISPLIT / 32;   // 16
#define LSUM_LOAD(it)                                                         \
  { _Pragma("unroll") for (int r = 0; r < 2; ++r) {                           \
      int s = tid + r * 256; int row = s >> 4, c = s & 15;                    \
      rt[r] = *(const int4*)(thb + (size_t)((it) * 32 + row) * NCI + c * 8); } }
#define LSUM_WRITE(buf)                                                       \
  { _Pragma("unroll") for (int r = 0; r < 2; ++r) {                           \
      int s = tid + r * 256; int row = s >> 4, c = s & 15;                    \
      *(int4*)(&thT[buf][row * 128 + ((c ^ (row & 7)) * 8)]) = rt[r]; } }
  LSUM_LOAD(0); LSUM_WRITE(0); __syncthreads();
  int cur = 0;
  const int swz = il & 7;
  for (int it = 0; it < NIT; ++it) {
    if (it + 1 < NIT) LSUM_LOAD(it + 1);
    f32x16 s16;
#pragma unroll
    for (int r = 0; r < 16; ++r) s16[r] = 0.f;
#pragma unroll
    for (int kk = 0; kk < 8; ++kk) {
      bf16x8 a = *(const bf16x8*)(&thT[cur][il * 128 + (((2 * kk + h) ^ swz) * 8)]);
      s16 = __builtin_amdgcn_mfma_f32_32x32x16_bf16(a, pf[kk], s16, 0, 0, 0);
    }
#pragma unroll
    for (int r = 0; r < 16; ++r) lsum += __expf(s16[r]);
    if (it + 1 < NIT) LSUM_WRITE(cur ^ 1);
    __syncthreads();
    cur ^= 1;
  }
  lsum += __shfl_xor(lsum, 32);
  if (h == 0)
    plsum[((size_t)(b * ISPLIT + iy) << 12) + j0 + w * 32 + il] = lsum;
#undef LSUM_LOAD
#undef LSUM_WRITE
}

// ---------------- attention, 32x32x16 MFMA (R19-verified) ----------------
__global__ __launch_bounds__(256, 2) void k_attn(
    const short* __restrict__ phiB, const short* __restrict__ thetaB,
    const short* __restrict__ gB, short* __restrict__ omidP) {
  __shared__ short phiT[2][32 * 128];   // 8KB each, chunk-swizzled ^(row&7)
  __shared__ short gT[2][256 * 32];     // 16KB each, slot-swizzled ^((row>>1)&3)
  __shared__ short pT[4][32 * 32];      // 2KB per wave, slot-swizzled
  const int tid = threadIdx.x, lane = tid & 63, w = tid >> 6;
  const int il = lane & 31, h = lane >> 5;
  const int key = (il >> 1) & 3;        // 16B-slot swizzle key (row = il)
  const int i0 = blockIdx.x * 128, jq = blockIdx.y, b = blockIdx.z;
  const short* phb = phiB + (size_t)b * NPOS * NCI;
  const short* thb = thetaB + (size_t)b * NPOS * NCI;
  const short* gb = gB + (size_t)b * NC * NPOS;
  short* om = omidP + ((size_t)(jq * NB + b)) * NC * NPOS;

  bf16x8 tf[8];
  {
    const short* tr = thb + (size_t)(i0 + w * 32 + il) * NCI;
#pragma unroll
    for (int kk = 0; kk < 8; ++kk) tf[kk] = *(const bf16x8*)(tr + kk * 16 + h * 8);
  }
  f32x16 acc[8];
#pragma unroll
  for (int i = 0; i < 8; ++i)
#pragma unroll
    for (int r = 0; r < 16; ++r) acc[i][r] = 0.f;

  int4 rphi[2], rg[4];
  const int NT = 32;                    // 32 j-tiles of 32 per quarter
  const int jbase = jq * 32;
#define ATTN_LOAD(jt)                                                          \
  { _Pragma("unroll") for (int r = 0; r < 2; ++r) {                            \
      int s = tid + r * 256; int row = s >> 4, c = s & 15;                     \
      rphi[r] = *(const int4*)(phb + (size_t)((jbase + (jt)) * 32 + row) * NCI + c * 8); } \
    _Pragma("unroll") for (int r = 0; r < 4; ++r) {                            \
      int s = tid + r * 256; int cc = s >> 2, c4 = s & 3;                      \
      rg[r] = *(const int4*)(gb + (size_t)cc * NPOS + (jbase + (jt)) * 32 + c4 * 8); } }
#define ATTN_WRITE(buf)                                                        \
  { _Pragma("unroll") for (int r = 0; r < 2; ++r) {                            \
      int s = tid + r * 256; int row = s >> 4, c = s & 15;                     \
      *(int4*)(&phiT[buf][row * 128 + ((c ^ (row & 7)) * 8)]) = rphi[r]; }     \
    _Pragma("unroll") for (int r = 0; r < 4; ++r) {                            \
      int s = tid + r * 256; int cc = s >> 2, c4 = s & 3;                      \
      *(int4*)(&gT[buf][cc * 32 + ((c4 ^ ((cc >> 1) & 3)) * 8)]) = rg[r]; } }
  ATTN_LOAD(0); ATTN_WRITE(0); __syncthreads();
  int cur = 0;
  for (int jt = 0; jt < NT; ++jt) {
    if (jt + 1 < NT) ATTN_LOAD(jt + 1);
    {
      const short* PH = &phiT[cur][0];
      short* PW = &pT[w][0];
      // ---- S^T: 32 j x 32 i, K=128 via 8 mfma 32x32x16 ----
      f32x16 s16;
#pragma unroll
      for (int r = 0; r < 16; ++r) s16[r] = 0.f;
      const int swp = il & 7;           // phi chunk swizzle (row = j = il)
#pragma unroll
      for (int kk = 0; kk < 8; ++kk) {
        bf16x8 a = *(const bf16x8*)(PH + il * 128 + (((2 * kk + h) ^ swp) * 8));
        s16 = __builtin_amdgcn_mfma_f32_32x32x16_bf16(a, tf[kk], s16, 0, 0, 0);
      }
      // lane holds S^T[j=(r&3)+8*(r>>2)+4h][i = i0+w*32+il]; P = exp(S)
#pragma unroll
      for (int g2 = 0; g2 < 4; ++g2) {
        unsigned short p0 = f2bf(__expf(s16[4 * g2 + 0]));
        unsigned short p1 = f2bf(__expf(s16[4 * g2 + 1]));
        unsigned short p2 = f2bf(__expf(s16[4 * g2 + 2]));
        unsigned short p3 = f2bf(__expf(s16[4 * g2 + 3]));
        unsigned int lo = (unsigned int)p0 | ((unsigned int)p1 << 16);
        unsigned int hi2 = (unsigned int)p2 | ((unsigned int)p3 << 16);
        *(uint2*)(PW + il * 32 + ((g2 ^ key) * 8) + 4 * h) = make_uint2(lo, hi2);
      }
      // ---- PV: wave's 32 i x all 256 cc ----
      const short* GT = &gT[cur][0];
      bf16x8 pa[2];
#pragma unroll
      for (int jh2 = 0; jh2 < 2; ++jh2)
        pa[jh2] = *(const bf16x8*)(PW + il * 32 + (((2 * jh2 + h) ^ key) * 8));
#pragma unroll
      for (int ct = 0; ct < 8; ++ct) {
#pragma unroll
        for (int jh2 = 0; jh2 < 2; ++jh2) {
          bf16x8 bg = *(const bf16x8*)(GT + (ct * 32 + il) * 32 + (((2 * jh2 + h) ^ key) * 8));
          acc[ct] = __builtin_amdgcn_mfma_f32_32x32x16_bf16(pa[jh2], bg, acc[ct], 0, 0, 0);
        }
      }
    }
    if (jt + 1 < NT) ATTN_WRITE(cur ^ 1);
    __syncthreads();
    cur ^= 1;
  }
#pragma unroll
  for (int ct = 0; ct < 8; ++ct)
#pragma unroll
    for (int g2 = 0; g2 < 4; ++g2) {
      __align__(8) short pv[4];
#pragma unroll
      for (int e = 0; e < 4; ++e) pv[e] = (short)f2bf(acc[ct][4 * g2 + e]);
      size_t o = (size_t)(ct * 32 + il) * NPOS + i0 + w * 32 + 8 * g2 + 4 * h;
      *(uint2*)(om + o) = *(const uint2*)pv;
    }
#undef ATTN_LOAD
#undef ATTN_WRITE
}

extern "C" void kernel_launch(void* const* d_in, const int* in_sizes, int n_in,
                              void* d_out, int out_size, void* d_ws, size_t ws_size,
                              hipStream_t stream) {
  (void)in_sizes; (void)n_in; (void)out_size; (void)ws_size;
  const float* x0      = (const float*)d_in[0];
  const float* x       = (const float*)d_in[1];
  const float* x_dsm   = (const float*)d_in[2];
  const float* w_phi   = (const float*)d_in[3];
  const float* w_theta = (const float*)d_in[4];
  const float* w_g     = (const float*)d_in[5];
  const float* w_mask  = (const float*)d_in[6];
  float* outp = (float*)d_out;

  short* sp = (short*)d_ws;
  short* wb_phi   = sp; sp += 32768;
  short* wb_theta = sp; sp += 32768;
  short* wb_g     = sp; sp += 131072;
  short* wb_mask  = sp; sp += 131072;
  short* xT   = sp; sp += (size_t)NB * NPOS * NC;          // 8MB
  short* xdT  = sp; sp += (size_t)NB * NPOS * NC;          // 8MB
  short* x0T  = sp; sp += (size_t)NB * NPOS * NC2;         // 16MB
  short* phiB   = sp; sp += (size_t)NB * NPOS * NCI;       // 4MB
  short* thetaB = sp; sp += (size_t)NB * NPOS * NCI;       // 4MB
  short* gBuf   = sp; sp += (size_t)NB * NC * NPOS;        // 8MB
  float* plsum = (float*)sp;                               // [b][ISPLIT][NPOS]
  short* omidP = xT;       // 4 bf16 partials x 8MB = 32MB, aliases dead xT/xdT/x0T
  short* omidT = phiB;     // 8MB bf16 [b][p][cc], aliases dead phiB/thetaB

  // transpose-casts + weight cast (y==16)
  k_tcast_all<<<dim3(64, 17, NB), 256, 0, stream>>>(
      x, x_dsm, x0, xT, xdT, x0T,
      w_phi, wb_phi, w_theta, wb_theta, w_g, wb_g, w_mask, wb_mask);

  // phi + theta in one dispatch (z<NB: phi from xT; z>=NB: theta from xdT)
  k_gemm<true, false, false, true><<<dim3(64, 2, 2 * NB), 256, 0, stream>>>(
      wb_phi, xT, phiB, nullptr, nullptr, wb_theta, xdT, thetaB,
      NC, NCI, 0, (size_t)NPOS * NC, (size_t)NPOS * NCI);

  k_lsum<<<dim3(NPOS / 128, ISPLIT, NB), 256, 0, stream>>>(phiB, thetaB, plsum);

  // g[cc][p] = (sum_c x0T[p][c] W_g[cc][c]) * (1/sum_t plsum[b][t][p])
  k_gemm<true, false, true, false><<<dim3(4, 64, NB), 256, 0, stream>>>(
      x0T, wb_g, gBuf, nullptr, plsum, nullptr, nullptr, nullptr,
      NC2, NPOS, (size_t)NPOS * NC2, 0, (size_t)NC * NPOS);

  k_attn<<<dim3(NPOS / 128, 4, NB), 256, 0, stream>>>(phiB, thetaB, gBuf, omidP);

  k_tcast4<<<dim3(64, 4, NB), 256, 0, stream>>>(omidP, omidT);

  k_gemm<false, true, false, false><<<dim3(8, 64, NB), 256, 0, stream>>>(
      omidT, wb_mask, outp, x0, nullptr, nullptr, nullptr, nullptr,
      NC, NPOS, (size_t)NPOS * NC, 0, (size_t)NC2 * NPOS);
}